// Round 1
// baseline (1020.841 us; speedup 1.0000x reference)
//
#include <hip/hip_runtime.h>

typedef unsigned short u16;
typedef unsigned int u32;
using f32x4 = __attribute__((ext_vector_type(4))) float;
using s16x8 = __attribute__((ext_vector_type(8))) short;
using u16x4 = __attribute__((ext_vector_type(4))) u16;

#define DEV __device__ __forceinline__

DEV float bf2f(u16 u) { union { u32 i; float f; } v; v.i = ((u32)u) << 16; return v.f; }
DEV u16 f2bf(float f) {
  union { float ff; u32 uu; } v; v.ff = f;
  u32 r = (v.uu + 0x7fffu + ((v.uu >> 16) & 1u)) >> 16;
  return (u16)r;
}

DEV void gl_lds16(const void* g, void* l) {
  __builtin_amdgcn_global_load_lds(
      (const __attribute__((address_space(1))) u32*)g,
      (__attribute__((address_space(3))) u32*)l, 16, 0, 0);
}

DEV void BAR() { __builtin_amdgcn_s_barrier(); }
DEV void LGKM0() { asm volatile("s_waitcnt lgkmcnt(0)" ::: "memory"); __builtin_amdgcn_sched_barrier(0); }
DEV void VM6() { asm volatile("s_waitcnt vmcnt(6)" ::: "memory"); }
DEV void VM0() { asm volatile("s_waitcnt vmcnt(0)" ::: "memory"); }
DEV void PRIO1() { __builtin_amdgcn_s_setprio(1); }
DEV void PRIO0() { __builtin_amdgcn_s_setprio(0); }

// ---------------- L2 normalize per frame, emit bf16 ----------------
__global__ __launch_bounds__(256) void k_l2norm(const float* __restrict__ x, u16* __restrict__ xn) {
  int r = blockIdx.x, t = threadIdx.x;
  const float* xr = x + (size_t)r * 2048;
  float v[8], s = 0.f;
#pragma unroll
  for (int i = 0; i < 8; i++) { v[i] = xr[t + i*256]; s += v[i]*v[i]; }
#pragma unroll
  for (int off = 32; off > 0; off >>= 1) s += __shfl_xor(s, off, 64);
  __shared__ float red[4];
  if ((t & 63) == 0) red[t >> 6] = s;
  __syncthreads();
  float inv = 1.f / fmaxf(sqrtf(red[0]+red[1]+red[2]+red[3]), 1e-12f);
  u16* xo = xn + (size_t)r * 2048;
#pragma unroll
  for (int i = 0; i < 8; i++) xo[t + i*256] = f2bf(v[i]*inv);
}

// ---------------- f32 -> bf16 ----------------
__global__ void k_cvt(const float* __restrict__ in, u16* __restrict__ out, int n4) {
  int i = blockIdx.x*256 + threadIdx.x, st = gridDim.x*256;
  for (; i < n4; i += st) {
    f32x4 v = ((const f32x4*)in)[i];
    u16x4 o;
    o[0] = f2bf(v[0]); o[1] = f2bf(v[1]); o[2] = f2bf(v[2]); o[3] = f2bf(v[3]);
    ((u16x4*)out)[i] = o;
  }
}

// ---------------- c1 [4096][512] -> c1ext bf16 rows 0..511 [640][4096] ----------------
__global__ __launch_bounds__(256) void k_transpose(const float* __restrict__ c1, u16* __restrict__ c1t) {
  __shared__ float tile[32][33];
  int k0 = blockIdx.x*32, n0 = blockIdx.y*32;
  int tx = threadIdx.x & 31, ty = threadIdx.x >> 5;
  for (int i = ty; i < 32; i += 8) tile[i][tx] = c1[(size_t)(k0+i)*512 + n0 + tx];
  __syncthreads();
  for (int i = ty; i < 32; i += 8) c1t[(size_t)(n0+i)*4096 + k0 + tx] = f2bf(tile[tx][i]);
}

// ---------------- bf16 MFMA NT GEMM, 128x128 tile (kept for GEMM2) ----------------
template<bool WF32, bool WBF16>
__global__ __launch_bounds__(256) void k_gemm(
    const u16* __restrict__ A, const u16* __restrict__ Bt, const float* __restrict__ bias,
    float* __restrict__ Cf, u16* __restrict__ Cb, int N, int K, int Nlim,
    int MT, int NT, int swz) {
  __shared__ u16 As[128*32];
  __shared__ u16 Bs[128*32];
  int bid = blockIdx.x, mt, nt;
  if (swz) {
    int mg = (MT + 7) >> 3;
    int gid = bid >> 5, gl = bid & 31;
    mt = (gid % mg)*8 + (gl & 7);
    nt = (gid / mg)*4 + (gl >> 3);
    if (mt >= MT) return;
  } else { mt = bid % MT; nt = bid / MT; }
  int t = threadIdx.x, wv = t >> 6;
  int quad = (t & 63) >> 4, lr = t & 15;
  size_t m0 = (size_t)mt * 128, n0 = (size_t)nt * 128;
  int wm = wv & 1, wn = wv >> 1;
  int srow = t >> 2;
  int scol = (((t & 3) ^ ((t >> 3) & 3)) * 8);   // XOR-swizzled k-chunk
  const u16* gA = A + (m0 + srow)*(size_t)K + scol;
  const u16* gB = Bt + (n0 + srow)*(size_t)K + scol;
  u16* lA = &As[wv*512];
  u16* lB = &Bs[wv*512];
  int xq = (quad ^ ((lr >> 1) & 3)) * 8;          // matching frag-read chunk
  f32x4 acc[4][4];
#pragma unroll
  for (int i = 0; i < 4; i++)
#pragma unroll
    for (int j = 0; j < 4; j++) acc[i][j] = (f32x4){0.f,0.f,0.f,0.f};
  for (int k0 = 0; k0 < K; k0 += 32) {
    gl_lds16(gA + k0, lA);
    gl_lds16(gA + (size_t)64*K + k0, lA + 2048);
    gl_lds16(gB + k0, lB);
    gl_lds16(gB + (size_t)64*K + k0, lB + 2048);
    __syncthreads();
    s16x8 af[4], bfr[4];
#pragma unroll
    for (int i = 0; i < 4; i++) {
      af[i]  = *(const s16x8*)&As[(wm*64 + i*16 + lr)*32 + xq];
      bfr[i] = *(const s16x8*)&Bs[(wn*64 + i*16 + lr)*32 + xq];
    }
#pragma unroll
    for (int i = 0; i < 4; i++)
#pragma unroll
      for (int j = 0; j < 4; j++)
        acc[i][j] = __builtin_amdgcn_mfma_f32_16x16x32_bf16(af[i], bfr[j], acc[i][j], 0, 0, 0);
    __syncthreads();
  }
#pragma unroll
  for (int j = 0; j < 4; j++) {
    size_t nn = n0 + wn*64 + j*16 + lr;
    if ((int)nn >= Nlim) continue;
    float bj = bias ? bias[nn] : 0.f;
#pragma unroll
    for (int i = 0; i < 4; i++) {
      size_t mr = m0 + wm*64 + i*16 + quad*4;
#pragma unroll
      for (int r = 0; r < 4; r++) {
        float v = acc[i][j][r] + bj;
        if (WF32)  Cf[(mr + r)*N + nn] = v;
        if (WBF16) Cb[(mr + r)*N + nn] = f2bf(v);
      }
    }
  }
}

// ---------------- 256x256 8-phase bf16 MFMA GEMM (T2+T3+T4+T5), BK=64 ----------------
// C[m,n] = sum_k A[m,k]*Bt[n,k] (+bias). 512 threads = 8 waves (2M x 4N),
// double-buffered 128 KiB LDS, counted vmcnt(6) across barriers, setprio'd
// 16-MFMA clusters. K must be a multiple of 64, T=K/64 >= 2.
// LDS chunk swizzle: logical 16B chunk c of row r stored at phys chunk c^(r&7);
// applied on the global SOURCE of global_load_lds and on fragment reads (rule #21).
// A rows beyond M read adjacent workspace (allocated); stores are M-guarded.
template<bool WF32, bool WBF16>
__global__ __launch_bounds__(512, 2) void k_gemm256(
    const u16* __restrict__ A, const u16* __restrict__ Bt, const float* __restrict__ bias,
    float* __restrict__ Cf, u16* __restrict__ Cb,
    int M, int N, int K, int Nlim, int MT, int NT, int swz) {
  constexpr int TILE = 256*64;                 // u16 elems per matrix per buffer
  __shared__ u16 lds[4*TILE];                  // [buf][A|B][256][64] = 128 KiB
  int bid = blockIdx.x;
  if (swz) { int c = (MT*NT) >> 3; bid = (bid & 7)*c + (bid >> 3); }  // grid%8==0
  int mt = bid % MT, nt = bid / MT;
  int t = threadIdx.x, wv = t >> 6, lane = t & 63;
  int quad = lane >> 4, lr = lane & 15;
  int wm = wv >> 2, wn = wv & 3;               // 2M x 4N waves
  size_t m0 = (size_t)mt * 256, n0 = (size_t)nt * 256;
  // staging addressing: lane l covers (row = 8*wv + (l>>3), phys chunk l&7);
  // pre-swizzled global source chunk = (l&7) ^ (l>>3)
  int srow = wv*8 + (lane >> 3);
  int schunk = ((lane & 7) ^ (lane >> 3)) * 8;
  const u16* gA = A  + (size_t)(m0 + srow)*K + schunk;
  const u16* gB = Bt + (size_t)(n0 + srow)*K + schunk;
  size_t row64 = (size_t)64 * K;               // 64-row advance in source
  int lofs = wv*512;                           // wave's LDS slot within a 64-row round
  // fragment read addressing (phys chunk = logical ^ (row&7), row&7 == lr&7)
  int raBase = (wm*128 + lr)*64;
  int rbBase = (wn*64  + lr)*64;
  int pc0 = ((0 + quad) ^ (lr & 7)) * 8;       // k-slice 0 chunks
  int pc1 = ((4 + quad) ^ (lr & 7)) * 8;       // k-slice 1 chunks
  f32x4 acc[8][4];
#pragma unroll
  for (int i = 0; i < 8; i++)
#pragma unroll
    for (int j = 0; j < 4; j++) acc[i][j] = (f32x4){0.f,0.f,0.f,0.f};

  int T = K >> 6;
  u16* A0 = lds;            u16* B0 = lds + TILE;
  u16* A1 = lds + 2*TILE;   u16* B1 = lds + 3*TILE;
  // ---- prologue: tile0 full (8 loads) + tile1 trio Ah0,Ah1,Bh0 (6 loads) ----
#pragma unroll
  for (int q = 0; q < 4; q++) gl_lds16(gA + q*row64, A0 + q*4096 + lofs);
#pragma unroll
  for (int q = 0; q < 4; q++) gl_lds16(gB + q*row64, B0 + q*4096 + lofs);
#pragma unroll
  for (int q = 0; q < 4; q++) gl_lds16(gA + 64 + q*row64, A1 + q*4096 + lofs);
  gl_lds16(gB + 64 + 0*row64, B1 + 0*4096 + lofs);
  gl_lds16(gB + 64 + 1*row64, B1 + 1*4096 + lofs);
  VM6();   // tile0 fully landed; tile1 trio still in flight
  BAR();

  for (int tt = 0; tt < T; ++tt) {
    u16* Ac = lds + (tt & 1)*(2*TILE);
    u16* Bc = Ac + TILE;
    u16* Bn = lds + ((tt + 1) & 1)*(2*TILE) + TILE;
    s16x8 a[8], b[4];
    // ---- P0: read ks0 frags; issue Bh1 of tile tt+1 (-> other buffer) ----
#pragma unroll
    for (int i = 0; i < 8; i++) a[i] = *(const s16x8*)&Ac[raBase + i*1024 + pc0];
#pragma unroll
    for (int j = 0; j < 4; j++) b[j] = *(const s16x8*)&Bc[rbBase + j*1024 + pc0];
    if (tt + 1 < T) {
      const u16* gB1 = gB + (size_t)(tt + 1)*64;
      gl_lds16(gB1 + 2*row64, Bn + 2*4096 + lofs);
      gl_lds16(gB1 + 3*row64, Bn + 3*4096 + lofs);
    }
    BAR(); LGKM0();
    PRIO1();
#pragma unroll
    for (int i = 0; i < 8; i++) {
      acc[i][0] = __builtin_amdgcn_mfma_f32_16x16x32_bf16(a[i], b[0], acc[i][0], 0, 0, 0);
      acc[i][1] = __builtin_amdgcn_mfma_f32_16x16x32_bf16(a[i], b[1], acc[i][1], 0, 0, 0);
    }
    PRIO0(); BAR();
    // ---- P1: MFMA only (ks0, j=2,3) ----
    PRIO1();
#pragma unroll
    for (int i = 0; i < 8; i++) {
      acc[i][2] = __builtin_amdgcn_mfma_f32_16x16x32_bf16(a[i], b[2], acc[i][2], 0, 0, 0);
      acc[i][3] = __builtin_amdgcn_mfma_f32_16x16x32_bf16(a[i], b[3], acc[i][3], 0, 0, 0);
    }
    PRIO0(); BAR();
    // ---- P2: read ks1 frags (last reads of this buffer) ----
#pragma unroll
    for (int i = 0; i < 8; i++) a[i] = *(const s16x8*)&Ac[raBase + i*1024 + pc1];
#pragma unroll
    for (int j = 0; j < 4; j++) b[j] = *(const s16x8*)&Bc[rbBase + j*1024 + pc1];
    BAR(); LGKM0();
    PRIO1();
#pragma unroll
    for (int i = 0; i < 8; i++) {
      acc[i][0] = __builtin_amdgcn_mfma_f32_16x16x32_bf16(a[i], b[0], acc[i][0], 0, 0, 0);
      acc[i][1] = __builtin_amdgcn_mfma_f32_16x16x32_bf16(a[i], b[1], acc[i][1], 0, 0, 0);
    }
    PRIO0(); BAR();
    // ---- P3: issue trio of tile tt+2 into THIS buffer (all reads done); MFMA ks1 j23 ----
    if (tt + 2 < T) {
      const u16* gA2 = gA + (size_t)(tt + 2)*64;
      const u16* gB2 = gB + (size_t)(tt + 2)*64;
#pragma unroll
      for (int q = 0; q < 4; q++) gl_lds16(gA2 + q*row64, Ac + q*4096 + lofs);
      gl_lds16(gB2 + 0*row64, Bc + 0*4096 + lofs);
      gl_lds16(gB2 + 1*row64, Bc + 1*4096 + lofs);
    }
    BAR();
    PRIO1();
#pragma unroll
    for (int i = 0; i < 8; i++) {
      acc[i][2] = __builtin_amdgcn_mfma_f32_16x16x32_bf16(a[i], b[2], acc[i][2], 0, 0, 0);
      acc[i][3] = __builtin_amdgcn_mfma_f32_16x16x32_bf16(a[i], b[3], acc[i][3], 0, 0, 0);
    }
    PRIO0();
    if (tt + 2 < T) VM6();        // next tile fully staged; 3 half-tiles stay in flight
    else if (tt + 1 < T) VM0();   // tail: drain for final tile
    BAR();
  }

  // ---- epilogue ----
#pragma unroll
  for (int j = 0; j < 4; j++) {
    int nn = (int)n0 + wn*64 + j*16 + lr;
    if (nn >= Nlim) continue;
    float bj = bias ? bias[nn] : 0.f;
#pragma unroll
    for (int i = 0; i < 8; i++) {
      int mr = (int)m0 + wm*128 + i*16 + quad*4;
#pragma unroll
      for (int r = 0; r < 4; r++) {
        if (mr + r >= M) continue;
        float v = acc[i][j][r] + bj;
        if (WF32)  Cf[(size_t)(mr + r)*N + nn] = v;
        if (WBF16) Cb[(size_t)(mr + r)*N + nn] = f2bf(v);
      }
    }
  }
}

// ---------------- hb [9600][4096] -> hbT [32][512][2400] (bf16) ----------------
__global__ __launch_bounds__(256) void k_hbt(const u16* __restrict__ hb, u16* __restrict__ hbT) {
  __shared__ u16 tile[64*33];
  int nt = blockIdx.x, ft = blockIdx.y, b = blockIdx.z, t = threadIdx.x;
  int n0 = nt*32, f0 = ft*64;
  int rrel = t >> 6, g = (t >> 3) & 7, fi = (t & 7)*8;
  const u16* src = hb + ((size_t)(b*300 + (n0 >> 3) + rrel))*4096 + g*512 + f0 + fi;
  u16 v[8];
  *(u16x4*)v = *(const u16x4*)src;
  *(u16x4*)(v+4) = *(const u16x4*)(src+4);
  int nl = rrel*8 + g;
#pragma unroll
  for (int e = 0; e < 8; e++) tile[(fi+e)*33 + nl] = v[e];
  __syncthreads();
  int f = t >> 2, nc = (t & 3)*8;
  u16 o[8];
#pragma unroll
  for (int e = 0; e < 8; e++) o[e] = tile[f*33 + nc + e];
  u16* dst = hbT + ((size_t)b*512 + f0 + f)*2400 + n0 + nc;
  *(u16x4*)dst = *(u16x4*)o;
  *(u16x4*)(dst+4) = *(u16x4*)(o+4);
}

// ---------------- bn1 + softmax(K=64) + att(from ext cols) -> actT bf16 [32][64][2400] ----------------
__global__ __launch_bounds__(512) void k_softmax(const float* __restrict__ act_ext,
    const float* __restrict__ fc2_b,
    const float* __restrict__ g, const float* __restrict__ b,
    const float* __restrict__ mu, const float* __restrict__ var, u16* __restrict__ actT) {
  int m = blockIdx.x, t = threadIdx.x;
  int bb = m / 300, fr = m - bb*300;
  int gi = t >> 6, k = t & 63, c = t;
  float v = act_ext[(size_t)m*640 + c];
  v = (v - mu[c]) * rsqrtf(var[c] + 1e-5f) * g[c] + b[c];
  float mx = v;
#pragma unroll
  for (int off = 32; off > 0; off >>= 1) mx = fmaxf(mx, __shfl_xor(mx, off, 64));
  float e = __expf(v - mx);
  float s = e;
#pragma unroll
  for (int off = 32; off > 0; off >>= 1) s += __shfl_xor(s, off, 64);
  float attl = act_ext[(size_t)m*640 + 512 + gi] + fc2_b[gi];
  float attv = 1.f / (1.f + __expf(-attl));
  float r = (e / s) * attv;
  __shared__ u16 st[64*9];
  st[k*9 + gi] = f2bf(r);
  __syncthreads();
  if (t < 64) {
    u16 o[8];
#pragma unroll
    for (int e2 = 0; e2 < 8; e2++) o[e2] = st[t*9 + e2];
    u16* dst = actT + ((size_t)bb*64 + t)*2400 + fr*8;
    *(u16x4*)dst = *(u16x4*)o;
    *(u16x4*)(dst+4) = *(u16x4*)(o+4);
  }
}

// ---------------- a_sum[b,k] = sum_n actT[b,k,n] ----------------
__global__ __launch_bounds__(256) void k_asum(const u16* __restrict__ actT, float* __restrict__ a_sum) {
  int b = blockIdx.x, t = threadIdx.x;
  int k = t >> 2, q = t & 3;
  const u16* p = actT + ((size_t)b*64 + k)*2400 + q*600;
  float acc = 0.f;
  for (int j = 0; j < 600; j += 8) {
    u16x4 a0 = *(const u16x4*)(p + j);
    u16x4 a1 = *(const u16x4*)(p + j + 4);
    acc += bf2f(a0[0])+bf2f(a0[1])+bf2f(a0[2])+bf2f(a0[3])
         + bf2f(a1[0])+bf2f(a1[1])+bf2f(a1[2])+bf2f(a1[3]);
  }
  __shared__ float red[256];
  red[t] = acc;
  __syncthreads();
  if (t < 64) a_sum[b*64 + t] = red[t*4] + red[t*4+1] + red[t*4+2] + red[t*4+3];
}

// ---------------- vlad MFMA: P2[ns][b][f][k] = sum_{n in chunk} hbT[b][f][n]*actT[b][k][n] ----------------
__global__ __launch_bounds__(256) void k_vlad(const u16* __restrict__ hbT, const u16* __restrict__ actT,
                                              float* __restrict__ P2) {
  __shared__ u16 As[128*32];
  __shared__ u16 Bs[64*32];
  int t = threadIdx.x, wv = t >> 6;
  int quad = (t & 63) >> 4, lr = t & 15;
  int ft = blockIdx.x, b = blockIdx.y, ns = blockIdx.z;
  int wm = wv & 1, wn = wv >> 1;
  int srow = t >> 2;
  int scol = (((t & 3) ^ ((t >> 3) & 3)) * 8);
  int xq = (quad ^ ((lr >> 1) & 3)) * 8;
  const u16* gA = hbT + ((size_t)b*512 + ft*128 + srow)*2400 + ns*480 + scol;
  const u16* gB = actT + ((size_t)b*64 + srow)*2400 + ns*480 + scol;
  u16* lA = &As[wv*512];
  u16* lB = &Bs[wv*512];
  f32x4 acc[4][2];
#pragma unroll
  for (int i = 0; i < 4; i++)
#pragma unroll
    for (int j = 0; j < 2; j++) acc[i][j] = (f32x4){0.f,0.f,0.f,0.f};
  for (int k0 = 0; k0 < 480; k0 += 32) {
    gl_lds16(gA + k0, lA);
    gl_lds16(gA + (size_t)64*2400 + k0, lA + 2048);
    gl_lds16(gB + k0, lB);
    __syncthreads();
    s16x8 af[4], bfr[2];
#pragma unroll
    for (int i = 0; i < 4; i++)
      af[i] = *(const s16x8*)&As[(wm*64 + i*16 + lr)*32 + xq];
#pragma unroll
    for (int j = 0; j < 2; j++)
      bfr[j] = *(const s16x8*)&Bs[(wn*32 + j*16 + lr)*32 + xq];
#pragma unroll
    for (int i = 0; i < 4; i++)
#pragma unroll
      for (int j = 0; j < 2; j++)
        acc[i][j] = __builtin_amdgcn_mfma_f32_16x16x32_bf16(af[i], bfr[j], acc[i][j], 0, 0, 0);
    __syncthreads();
  }
  size_t base = ((size_t)ns*32 + b)*512*64;
#pragma unroll
  for (int j = 0; j < 2; j++) {
    int kc = wn*32 + j*16 + lr;
#pragma unroll
    for (int i = 0; i < 4; i++) {
      int f = ft*128 + wm*64 + i*16 + quad*4;
#pragma unroll
      for (int r = 0; r < 4; r++)
        P2[base + (size_t)(f + r)*64 + kc] = acc[i][j][r];
    }
  }
}

// ---------------- sum partials, subtract a, intra-norm over f, bn2 -> vladn [32][32768] ----------------
__global__ __launch_bounds__(256) void k_norm2(const float* __restrict__ P2, const float* __restrict__ a_sum,
    const float* __restrict__ c2, const float* __restrict__ g, const float* __restrict__ b,
    const float* __restrict__ mu, const float* __restrict__ var, float* __restrict__ out) {
  int k = blockIdx.x, bb = blockIdx.y, t = threadIdx.x;
  float as = a_sum[bb*64 + k];
  int f0 = t, f1 = t + 256;
  const size_t PS = (size_t)32*512*64;
  size_t base = (size_t)bb*512*64;
  float x0 = 0.f, x1 = 0.f;
#pragma unroll
  for (int ns = 0; ns < 5; ns++) {
    x0 += P2[ns*PS + base + (size_t)f0*64 + k];
    x1 += P2[ns*PS + base + (size_t)f1*64 + k];
  }
  x0 -= as * c2[f0*64 + k];
  x1 -= as * c2[f1*64 + k];
  float s = x0*x0 + x1*x1;
#pragma unroll
  for (int off = 32; off > 0; off >>= 1) s += __shfl_xor(s, off, 64);
  __shared__ float red[4];
  if ((t & 63) == 0) red[t >> 6] = s;
  __syncthreads();
  float inv = 1.f / fmaxf(sqrtf(red[0]+red[1]+red[2]+red[3]), 1e-12f);
  int c0 = f0*64 + k, c1 = f1*64 + k;
  out[(size_t)bb*32768 + c0] = (x0*inv - mu[c0]) * rsqrtf(var[c0]+1e-5f) * g[c0] + b[c0];
  out[(size_t)bb*32768 + c1] = (x1*inv - mu[c1]) * rsqrtf(var[c1]+1e-5f) * g[c1] + b[c1];
}

// ---------------- split-K small-M MFMA GEMM ----------------
__global__ __launch_bounds__(256) void k_skgemm(
    const float* __restrict__ A, const float* __restrict__ W,
    float* __restrict__ P, int N, int K, int KC, int Npad) {
  constexpr int LDB = 72;
  __shared__ u16 Bs[128*LDB];
  __shared__ u16 As[32*LDB];
  int t = threadIdx.x;
  int wv = t >> 6, quad = (t & 63) >> 4, lr = t & 15;
  int n0 = blockIdx.x * 128;
  size_t kc0 = (size_t)blockIdx.y * KC;
  f32x4 acc[2][2];
#pragma unroll
  for (int i = 0; i < 2; i++)
#pragma unroll
    for (int j = 0; j < 2; j++) acc[i][j] = (f32x4){0.f,0.f,0.f,0.f};
  int wl[8]; size_t wg[8];
#pragma unroll
  for (int i = 0; i < 8; i++) {
    int slot = i*256 + t;
    int r = slot >> 4, q = slot & 15;
    int row = n0 + r; if (row >= N) row = N - 1;
    wl[i] = r*LDB + q*4;
    wg[i] = (size_t)row*K + kc0 + q*4;
  }
  int al[2]; size_t ag[2];
#pragma unroll
  for (int i = 0; i < 2; i++) {
    int slot = i*256 + t;
    int r = slot >> 4, q = slot & 15;
    al[i] = r*LDB + q*4;
    ag[i] = (size_t)r*K + kc0 + q*4;
  }
  int nst = KC >> 6;
  f32x4 wv4[8], av4[2];
#pragma unroll
  for (int i = 0; i < 8; i++) wv4[i] = *(const f32x4*)(W + wg[i]);
#pragma unroll
  for (int i = 0; i < 2; i++) av4[i] = *(const f32x4*)(A + ag[i]);
  for (int s = 0; s < nst; s++) {
    if (s) __syncthreads();
#pragma unroll
    for (int i = 0; i < 8; i++) {
      u16x4 o;
      o[0] = f2bf(wv4[i][0]); o[1] = f2bf(wv4[i][1]);
      o[2] = f2bf(wv4[i][2]); o[3] = f2bf(wv4[i][3]);
      *(u16x4*)&Bs[wl[i]] = o;
    }
#pragma unroll
    for (int i = 0; i < 2; i++) {
      u16x4 o;
      o[0] = f2bf(av4[i][0]); o[1] = f2bf(av4[i][1]);
      o[2] = f2bf(av4[i][2]); o[3] = f2bf(av4[i][3]);
      *(u16x4*)&As[al[i]] = o;
    }
    __syncthreads();
    if (s + 1 < nst) {
      int off = (s + 1) * 64;
#pragma unroll
      for (int i = 0; i < 8; i++) wv4[i] = *(const f32x4*)(W + wg[i] + off);
#pragma unroll
      for (int i = 0; i < 2; i++) av4[i] = *(const f32x4*)(A + ag[i] + off);
    }
#pragma unroll
    for (int ks = 0; ks < 2; ks++) {
      s16x8 af[2];
#pragma unroll
      for (int i = 0; i < 2; i++)
        af[i] = *(const s16x8*)&As[(i*16 + lr)*LDB + ks*32 + quad*8];
#pragma unroll
      for (int j = 0; j < 2; j++) {
        s16x8 bf = *(const s16x8*)&Bs[(wv*32 + j*16 + lr)*LDB + ks*32 + quad*8];
#pragma unroll
        for (int i = 0; i < 2; i++)
          acc[i][j] = __builtin_amdgcn_mfma_f32_16x16x32_bf16(af[i], bf, acc[i][j], 0, 0, 0);
      }
    }
  }
#pragma unroll
  for (int i = 0; i < 2; i++)
#pragma unroll
    for (int j = 0; j < 2; j++) {
      int n = n0 + wv*32 + j*16 + lr;
#pragma unroll
      for (int r = 0; r < 4; r++) {
        int m = i*16 + quad*4 + r;
        P[((size_t)blockIdx.y*32 + m)*Npad + n] = acc[i][j][r];
      }
    }
}

// ---------------- split-K reduce + epilogue ----------------
template<int EPI>
__global__ __launch_bounds__(256) void k_skred(const float* __restrict__ P, int KSPLIT, int N, int Npad,
    const float* __restrict__ bias, const float* __restrict__ bg, const float* __restrict__ bb,
    const float* __restrict__ bm, const float* __restrict__ bv, float* __restrict__ C) {
  int idx = blockIdx.x*256 + threadIdx.x;
  if (idx >= 32*N) return;
  int m = idx / N, n = idx - m*N;
  float s = 0.f;
  for (int k = 0; k < KSPLIT; k++) s += P[((size_t)k*32 + m)*Npad + n];
  float v = s + (bias ? bias[n] : 0.f);
  if (EPI == 1 || EPI == 2) {
    v = (v - bm[n]) * rsqrtf(bv[n] + 1e-5f) * bg[n] + bb[n];
    if (EPI == 2) v = fmaxf(v, 0.f);
  } else if (EPI == 3) {
    v = 1.f / (1.f + __expf(-v));
  }
  C[idx] = v;
}

// ---------------- elementwise multiply ----------------
__global__ void k_mul(const float* __restrict__ a, const float* __restrict__ b, float* __restrict__ o, int n) {
  int i = blockIdx.x*256 + threadIdx.x;
  if (i < n) o[i] = a[i]*b[i];
}

extern "C" void kernel_launch(void* const* d_in, const int* in_sizes, int n_in,
                              void* d_out, int out_size, void* d_ws, size_t ws_size,
                              hipStream_t stream) {
  (void)in_sizes; (void)n_in; (void)out_size; (void)ws_size;
  const float* x      = (const float*)d_in[0];
  const float* fc1_w  = (const float*)d_in[1];
  const float* fc1_b  = (const float*)d_in[2];
  const float* fc2_w  = (const float*)d_in[3];
  const float* fc2_b  = (const float*)d_in[4];
  const float* c1     = (const float*)d_in[5];
  const float* c2     = (const float*)d_in[6];
  const float* bn1_g  = (const float*)d_in[7];
  const float* bn1_b  = (const float*)d_in[8];
  const float* bn1_m  = (const float*)d_in[9];
  const float* bn1_v  = (const float*)d_in[10];
  const float* bn2_g  = (const float*)d_in[11];
  const float* bn2_b  = (const float*)d_in[12];
  const float* bn2_m  = (const float*)d_in[13];
  const float* bn2_v  = (const float*)d_in[14];
  const float* cgf_w  = (const float*)d_in[15];
  const float* cgf_b  = (const float*)d_in[16];
  const float* cgbn_g = (const float*)d_in[17];
  const float* cgbn_b = (const float*)d_in[18];
  const float* cgbn_m = (const float*)d_in[19];
  const float* cgbn_v = (const float*)d_in[20];
  const float* g1_w   = (const float*)d_in[21];
  const float* g1_b   = (const float*)d_in[22];
  const float* gbn_g  = (const float*)d_in[23];
  const float* gbn_b  = (const float*)d_in[24];
  const float* gbn_m  = (const float*)d_in[25];
  const float* gbn_v  = (const float*)d_in[26];
  const float* g2_w   = (const float*)d_in[27];
  const float* g2_b   = (const float*)d_in[28];
  const float* fc3_w  = (const float*)d_in[29];
  const float* fc3_b  = (const float*)d_in[30];

  char* w = (char*)d_ws;
  // region [0, 78643200): xn + w1b during phase 1; hbT after GEMM1
  u16*   xn    = (u16*)  (w + 0);                 // 39,321,600
  u16*   w1b   = (u16*)  (w + 39321600);          // 16,777,216
  u16*   hbT   = (u16*)  (w + 0);                 // 78,643,200 (after GEMM1)
  u16*   hb    = (u16*)  (w + 78643200);          // 78,643,200
  u16*   c1ext = (u16*)  (w + 157286400);         // 640*4096*2 = 5,242,880
  float* actx  = (float*)(w + 162529280);         // 9600*640*4 = 24,576,000
  u16*   actT  = (u16*)  (w + 187105280);         // 32*64*2400*2 = 9,830,400
  float* P2    = (float*)(w + 196935680);         // 5*32*512*64*4 = 20,971,520
  float* P     = (float*)(w + 196935680);         // skgemm partials reuse P2 region
  float* a_sum = (float*)(w + 217907200);         // 8,192
  float* vladn = (float*)(w + 217915392);         // 4,194,304
  float* y     = (float*)(w + 222109696);         // 262,144
  float* z     = (float*)(w + 222371840);         // 32,768
  float* gate  = (float*)(w + 222404608);         // 262,144
  float* yg    = (float*)(w + 222666752);         // 262,144
  // total ~222.9 MB

  k_l2norm<<<9600, 256, 0, stream>>>(x, xn);
  k_cvt<<<2048, 256, 0, stream>>>(fc1_w, w1b, (4096*2048)/4);
  k_transpose<<<dim3(128, 16), 256, 0, stream>>>(c1, c1ext);
  k_cvt<<<32, 256, 0, stream>>>(fc2_w, c1ext + (size_t)512*4096, (8*4096)/4);
  // GEMM1: h = xn @ fc1_w.T + fc1_b -> bf16 [9600][4096]; 256^2 8-phase kernel.
  // MT=38 (tail tile rows 9472..9727: A reads spill into w1b region - allocated,
  // garbage rows guarded at store), NT=16, grid 608 (%8==0 -> XCD swizzle ok).
  k_gemm256<false, true><<<608, 512, 0, stream>>>(xn, w1b, fc1_b, nullptr, hb,
                                                  9600, 4096, 2048, 4096, 38, 16, 1);
  // hb -> hbT [32][512][2400] (overwrites xn/w1b)
  k_hbt<<<dim3(75, 8, 32), 256, 0, stream>>>(hb, hbT);
  // GEMM2+att: act_ext = h @ [c1 | fc2_w].T -> f32 [9600][640] (store cols < 520)
  k_gemm<true, false><<<375, 256, 0, stream>>>(hb, c1ext, nullptr, actx, nullptr, 640, 4096, 520, 75, 5, 0);
  // bn1 + softmax + att -> actT bf16 [32][64][2400]
  k_softmax<<<9600, 512, 0, stream>>>(actx, fc2_b, bn1_g, bn1_b, bn1_m, bn1_v, actT);
  k_asum<<<32, 256, 0, stream>>>(actT, a_sum);
  // vlad partials
  k_vlad<<<dim3(4, 32, 5), 256, 0, stream>>>(hbT, actT, P2);
  k_norm2<<<dim3(64, 32), 256, 0, stream>>>(P2, a_sum, c2, bn2_g, bn2_b, bn2_m, bn2_v, vladn);

  // cgf: y = BN(vladn @ cgf_w.T + cgf_b)   N=2048, K=32768, KSPLIT=64, KC=512
  k_skgemm<<<dim3(16, 64), 256, 0, stream>>>(vladn, cgf_w, P, 2048, 32768, 512, 2048);
  k_skred<1><<<256, 256, 0, stream>>>(P, 64, 2048, 2048, cgf_b, cgbn_g, cgbn_b, cgbn_m, cgbn_v, y);
  // g1: z = relu(BN(y @ g1_w.T + g1_b))    N=256, K=2048, KSPLIT=32, KC=64
  k_skgemm<<<dim3(2, 32), 256, 0, stream>>>(y, g1_w, P, 256, 2048, 64, 256);
  k_skred<2><<<32, 256, 0, stream>>>(P, 32, 256, 256, g1_b, gbn_g, gbn_b, gbn_m, gbn_v, z);
  // g2: gate = sigmoid(z @ g2_w.T + g2_b)  N=2048, K=256, KSPLIT=4, KC=64
  k_skgemm<<<dim3(16, 4), 256, 0, stream>>>(z, g2_w, P, 2048, 256, 64, 2048);
  k_skred<3><<<256, 256, 0, stream>>>(P, 4, 2048, 2048, g2_b, nullptr, nullptr, nullptr, nullptr, gate);
  k_mul<<<256, 256, 0, stream>>>(y, gate, yg, 65536);
  // fc3: out = yg @ fc3_w.T + fc3_b        N=3862 (pad 3968), K=2048, KSPLIT=16, KC=128
  k_skgemm<<<dim3(31, 16), 256, 0, stream>>>(yg, fc3_w, P, 3862, 2048, 128, 3968);
  k_skred<0><<<483, 256, 0, stream>>>(P, 16, 3862, 3968, fc3_b, nullptr, nullptr, nullptr, nullptr, (float*)d_out);
}

// Round 2
// 1003.265 us; speedup vs baseline: 1.0175x; 1.0175x over previous
//
#include <hip/hip_runtime.h>

typedef unsigned short u16;
typedef unsigned int u32;
using f32x4 = __attribute__((ext_vector_type(4))) float;
using s16x8 = __attribute__((ext_vector_type(8))) short;
using u16x4 = __attribute__((ext_vector_type(4))) u16;

#define DEV __device__ __forceinline__

DEV float bf2f(u16 u) { union { u32 i; float f; } v; v.i = ((u32)u) << 16; return v.f; }
DEV u16 f2bf(float f) {
  union { float ff; u32 uu; } v; v.ff = f;
  u32 r = (v.uu + 0x7fffu + ((v.uu >> 16) & 1u)) >> 16;
  return (u16)r;
}

DEV void gl_lds16(const void* g, void* l) {
  __builtin_amdgcn_global_load_lds(
      (const __attribute__((address_space(1))) u32*)g,
      (__attribute__((address_space(3))) u32*)l, 16, 0, 0);
}

DEV void BAR() { __builtin_amdgcn_s_barrier(); }
DEV void VM6() { asm volatile("s_waitcnt vmcnt(6)" ::: "memory"); }
DEV void VM0() { asm volatile("s_waitcnt vmcnt(0)" ::: "memory"); }
DEV void PRIO1() { __builtin_amdgcn_s_setprio(1); }
DEV void PRIO0() { __builtin_amdgcn_s_setprio(0); }
// lgkmcnt(0) + scheduling fence (rule #18: stops MFMA hoisting past the wait)
#define LGKM0S() do { asm volatile("s_waitcnt lgkmcnt(0)" ::: "memory"); \
                      __builtin_amdgcn_sched_barrier(0); } while (0)

// inline-asm ds_read_b128: invisible to the compiler's LDS<->global_load_lds
// aliasing model, so no conservative vmem drains get inserted before it.
#define DSR(d, a, OFF) asm volatile("ds_read_b128 %0, %1 offset:" #OFF \
                                    : "=&v"(d) : "v"(a))
#define READ12(A_, B_, aa, bb) do {                                            \
  unsigned a_ = (aa), b_ = (bb);                                               \
  DSR(A_[0], a_, 0);     DSR(A_[1], a_, 2048);                                 \
  DSR(A_[2], a_, 4096);  DSR(A_[3], a_, 6144);                                 \
  DSR(A_[4], a_, 8192);  DSR(A_[5], a_, 10240);                                \
  DSR(A_[6], a_, 12288); DSR(A_[7], a_, 14336);                                \
  DSR(B_[0], b_, 0);     DSR(B_[1], b_, 2048);                                 \
  DSR(B_[2], b_, 4096);  DSR(B_[3], b_, 6144);                                 \
} while (0)

#define MFMA32(A_, B_) do {                                                    \
  _Pragma("unroll")                                                            \
  for (int i_ = 0; i_ < 8; i_++) {                                             \
    acc[i_][0] = __builtin_amdgcn_mfma_f32_16x16x32_bf16(A_[i_], B_[0], acc[i_][0], 0, 0, 0); \
    acc[i_][1] = __builtin_amdgcn_mfma_f32_16x16x32_bf16(A_[i_], B_[1], acc[i_][1], 0, 0, 0); \
    acc[i_][2] = __builtin_amdgcn_mfma_f32_16x16x32_bf16(A_[i_], B_[2], acc[i_][2], 0, 0, 0); \
    acc[i_][3] = __builtin_amdgcn_mfma_f32_16x16x32_bf16(A_[i_], B_[3], acc[i_][3], 0, 0, 0); \
  }                                                                            \
} while (0)

// ---------------- L2 normalize per frame, emit bf16 ----------------
__global__ __launch_bounds__(256) void k_l2norm(const float* __restrict__ x, u16* __restrict__ xn) {
  int r = blockIdx.x, t = threadIdx.x;
  const float* xr = x + (size_t)r * 2048;
  float v[8], s = 0.f;
#pragma unroll
  for (int i = 0; i < 8; i++) { v[i] = xr[t + i*256]; s += v[i]*v[i]; }
#pragma unroll
  for (int off = 32; off > 0; off >>= 1) s += __shfl_xor(s, off, 64);
  __shared__ float red[4];
  if ((t & 63) == 0) red[t >> 6] = s;
  __syncthreads();
  float inv = 1.f / fmaxf(sqrtf(red[0]+red[1]+red[2]+red[3]), 1e-12f);
  u16* xo = xn + (size_t)r * 2048;
#pragma unroll
  for (int i = 0; i < 8; i++) xo[t + i*256] = f2bf(v[i]*inv);
}

// ---------------- f32 -> bf16 ----------------
__global__ void k_cvt(const float* __restrict__ in, u16* __restrict__ out, int n4) {
  int i = blockIdx.x*256 + threadIdx.x, st = gridDim.x*256;
  for (; i < n4; i += st) {
    f32x4 v = ((const f32x4*)in)[i];
    u16x4 o;
    o[0] = f2bf(v[0]); o[1] = f2bf(v[1]); o[2] = f2bf(v[2]); o[3] = f2bf(v[3]);
    ((u16x4*)out)[i] = o;
  }
}

// ---------------- c1 [4096][512] -> c1ext bf16 rows 0..511 [640][4096] ----------------
__global__ __launch_bounds__(256) void k_transpose(const float* __restrict__ c1, u16* __restrict__ c1t) {
  __shared__ float tile[32][33];
  int k0 = blockIdx.x*32, n0 = blockIdx.y*32;
  int tx = threadIdx.x & 31, ty = threadIdx.x >> 5;
  for (int i = ty; i < 32; i += 8) tile[i][tx] = c1[(size_t)(k0+i)*512 + n0 + tx];
  __syncthreads();
  for (int i = ty; i < 32; i += 8) c1t[(size_t)(n0+i)*4096 + k0 + tx] = f2bf(tile[tx][i]);
}

// ---------------- bf16 MFMA NT GEMM, 128x128 tile (kept for GEMM2) ----------------
template<bool WF32, bool WBF16>
__global__ __launch_bounds__(256) void k_gemm(
    const u16* __restrict__ A, const u16* __restrict__ Bt, const float* __restrict__ bias,
    float* __restrict__ Cf, u16* __restrict__ Cb, int N, int K, int Nlim,
    int MT, int NT, int swz) {
  __shared__ u16 As[128*32];
  __shared__ u16 Bs[128*32];
  int bid = blockIdx.x, mt, nt;
  if (swz) {
    int mg = (MT + 7) >> 3;
    int gid = bid >> 5, gl = bid & 31;
    mt = (gid % mg)*8 + (gl & 7);
    nt = (gid / mg)*4 + (gl >> 3);
    if (mt >= MT) return;
  } else { mt = bid % MT; nt = bid / MT; }
  int t = threadIdx.x, wv = t >> 6;
  int quad = (t & 63) >> 4, lr = t & 15;
  size_t m0 = (size_t)mt * 128, n0 = (size_t)nt * 128;
  int wm = wv & 1, wn = wv >> 1;
  int srow = t >> 2;
  int scol = (((t & 3) ^ ((t >> 3) & 3)) * 8);   // XOR-swizzled k-chunk
  const u16* gA = A + (m0 + srow)*(size_t)K + scol;
  const u16* gB = Bt + (n0 + srow)*(size_t)K + scol;
  u16* lA = &As[wv*512];
  u16* lB = &Bs[wv*512];
  int xq = (quad ^ ((lr >> 1) & 3)) * 8;          // matching frag-read chunk
  f32x4 acc[4][4];
#pragma unroll
  for (int i = 0; i < 4; i++)
#pragma unroll
    for (int j = 0; j < 4; j++) acc[i][j] = (f32x4){0.f,0.f,0.f,0.f};
  for (int k0 = 0; k0 < K; k0 += 32) {
    gl_lds16(gA + k0, lA);
    gl_lds16(gA + (size_t)64*K + k0, lA + 2048);
    gl_lds16(gB + k0, lB);
    gl_lds16(gB + (size_t)64*K + k0, lB + 2048);
    __syncthreads();
    s16x8 af[4], bfr[4];
#pragma unroll
    for (int i = 0; i < 4; i++) {
      af[i]  = *(const s16x8*)&As[(wm*64 + i*16 + lr)*32 + xq];
      bfr[i] = *(const s16x8*)&Bs[(wn*64 + i*16 + lr)*32 + xq];
    }
#pragma unroll
    for (int i = 0; i < 4; i++)
#pragma unroll
      for (int j = 0; j < 4; j++)
        acc[i][j] = __builtin_amdgcn_mfma_f32_16x16x32_bf16(af[i], bfr[j], acc[i][j], 0, 0, 0);
    __syncthreads();
  }
#pragma unroll
  for (int j = 0; j < 4; j++) {
    size_t nn = n0 + wn*64 + j*16 + lr;
    if ((int)nn >= Nlim) continue;
    float bj = bias ? bias[nn] : 0.f;
#pragma unroll
    for (int i = 0; i < 4; i++) {
      size_t mr = m0 + wm*64 + i*16 + quad*4;
#pragma unroll
      for (int r = 0; r < 4; r++) {
        float v = acc[i][j][r] + bj;
        if (WF32)  Cf[(mr + r)*N + nn] = v;
        if (WBF16) Cb[(mr + r)*N + nn] = f2bf(v);
      }
    }
  }
}

// ---------------- 256x256 bf16 MFMA GEMM, 2-phase/tile pipelined (asm ds_read) ----------------
// C[m,n] = sum_k A[m,k]*Bt[n,k] (+bias). 512 threads = 8 waves (2M x 4N),
// double-buffered 128 KiB LDS, counted vmcnt(6) so staging loads stay in
// flight across barriers; fragment reads are inline-asm ds_read_b128 so the
// compiler's LDS-vs-global_load_lds aliasing cannot insert vmem drains.
// Per tile: 2x {12 asm ds_read; lgkmcnt(0)+sched_barrier; 32 MFMA}; 3 barriers.
// Staging for tile tt+2 issues only after the barrier proving all reads of
// the shared buffer (tile tt) completed chip-wide.
// LDS chunk swizzle (both-sides): logical 16B chunk c of row r at phys c^(r&7),
// via pre-swizzled global source + XOR'd read addresses.
// swz==2: bijective XCD supertile map (19mt x 4nt per XCD; needs MT=38,NT=16).
template<bool WF32, bool WBF16>
__global__ __launch_bounds__(512, 2) void k_gemm256(
    const u16* __restrict__ A, const u16* __restrict__ Bt, const float* __restrict__ bias,
    float* __restrict__ Cf, u16* __restrict__ Cb,
    int M, int N, int K, int Nlim, int MT, int NT, int swz) {
  constexpr int TILE = 256*64;                 // u16 elems per matrix per buffer
  __shared__ u16 lds[4*TILE];                  // A0|B0|A1|B1, 32 KiB each
  int bid = blockIdx.x, mt, nt;
  if (swz == 2) {
    // one 19mt x 4nt supertile per XCD (grid 608 = 8*76, bijective)
    int x = bid & 7, w2 = bid >> 3;
    mt = (x & 1)*19 + w2 % 19;
    nt = (x >> 1)*4 + w2 / 19;
  } else if (swz == 1) {
    int c = (MT*NT) >> 3; int b2 = (bid & 7)*c + (bid >> 3);
    mt = b2 % MT; nt = b2 / MT;
  } else { mt = bid % MT; nt = bid / MT; }
  int t = threadIdx.x, wv = t >> 6, lane = t & 63;
  int quad = lane >> 4, lr = lane & 15;
  int wm = wv >> 2, wn = wv & 3;               // 2M x 4N waves
  size_t m0 = (size_t)mt * 256, n0 = (size_t)nt * 256;
  // staging: lane l covers (row 8*wv + (l>>3), phys chunk l&7); source chunk pre-swizzled
  int srow = wv*8 + (lane >> 3);
  int schunk = ((lane & 7) ^ (lane >> 3)) * 8;
  const u16* gA = A  + (size_t)(m0 + srow)*K + schunk;
  const u16* gB = Bt + (size_t)(n0 + srow)*K + schunk;
  size_t row64 = (size_t)64 * K;
  int lofs = wv*512;                           // wave's 1KiB slot per 64-row group
  // fragment read addresses (bytes); slice1 = ^64, buffer flip = ^0x10000
  unsigned ldsB = (unsigned)(size_t)lds;
  unsigned pc = (unsigned)((quad ^ (lr & 7)) << 4);
  unsigned aCur = ldsB + (unsigned)((wm*128 + lr)*128) + pc;
  unsigned bCur = ldsB + 32768u + (unsigned)((wn*64 + lr)*128) + pc;
  f32x4 acc[8][4];
#pragma unroll
  for (int i = 0; i < 8; i++)
#pragma unroll
    for (int j = 0; j < 4; j++) acc[i][j] = (f32x4){0.f,0.f,0.f,0.f};

  int T = K >> 6;
  u16* A0 = lds;            u16* B0 = lds + TILE;
  u16* A1 = lds + 2*TILE;   u16* B1 = lds + 3*TILE;
  // ---- prologue: tile0 full (8) + tile1 trio (6) ----
#pragma unroll
  for (int q = 0; q < 4; q++) gl_lds16(gA + q*row64, A0 + q*4096 + lofs);
#pragma unroll
  for (int q = 0; q < 4; q++) gl_lds16(gB + q*row64, B0 + q*4096 + lofs);
#pragma unroll
  for (int q = 0; q < 4; q++) gl_lds16(gA + 64 + q*row64, A1 + q*4096 + lofs);
  gl_lds16(gB + 64,          B1 + lofs);
  gl_lds16(gB + 64 + row64,  B1 + 4096 + lofs);
  VM6();          // tile0 resident; tile1 trio stays in flight
  BAR();

  s16x8 fa[8], fb[4];
  for (int tt = 0; tt < T; ++tt) {
    // ---- PhA: slice0 reads + Bh1(tt+1) issue + 32 MFMA ----
    READ12(fa, fb, aCur, bCur);
    if (tt + 1 < T) {
      const u16* gB1 = gB + (size_t)(tt + 1)*64;
      u16* Bq = lds + (((tt + 1) & 1)*2 + 1)*TILE;
      gl_lds16(gB1 + 2*row64, Bq + 2*4096 + lofs);
      gl_lds16(gB1 + 3*row64, Bq + 3*4096 + lofs);
    }
    LGKM0S();
    PRIO1(); MFMA32(fa, fb); PRIO0();
    BAR();                     // all slice0 reads of buffer P done chip-wide
    // ---- PhB: slice1 reads + 32 MFMA ----
    READ12(fa, fb, aCur ^ 64u, bCur ^ 64u);
    LGKM0S();
    PRIO1(); MFMA32(fa, fb); PRIO0();
    BAR();                     // ALL reads of tile tt done chip-wide -> buffer P writable
    // ---- stage tile tt+2 into buffer P; wait tile tt+1 residency ----
    if (tt + 2 < T) {
      const u16* gA2 = gA + (size_t)(tt + 2)*64;
      const u16* gB2 = gB + (size_t)(tt + 2)*64;
      u16* Ap = lds + ((tt & 1)*2)*TILE;
      u16* Bp = Ap + TILE;
#pragma unroll
      for (int q = 0; q < 4; q++) gl_lds16(gA2 + q*row64, Ap + q*4096 + lofs);
      gl_lds16(gB2,         Bp + lofs);
      gl_lds16(gB2 + row64, Bp + 4096 + lofs);
      VM6();                   // tile tt+1 fully landed; trio(tt+2) in flight
    } else if (tt + 1 < T) {
      VM0();                   // tail: drain for final tile
    }
    if (tt + 1 < T) BAR();     // residency barrier before reading buffer Q
    aCur ^= 0x10000u; bCur ^= 0x10000u;
  }

  // ---- epilogue (row-contiguous store order: i,r outer, j inner) ----
  float bj[4];
#pragma unroll
  for (int j = 0; j < 4; j++) {
    int nn = (int)n0 + wn*64 + j*16 + lr;
    bj[j] = (bias && nn < Nlim) ? bias[nn] : 0.f;
  }
#pragma unroll
  for (int i = 0; i < 8; i++) {
    int mrb = (int)m0 + wm*128 + i*16 + quad*4;
#pragma unroll
    for (int r = 0; r < 4; r++) {
      int mr = mrb + r;
      if (mr >= M) continue;
#pragma unroll
      for (int j = 0; j < 4; j++) {
        int nn = (int)n0 + wn*64 + j*16 + lr;
        if (nn >= Nlim) continue;
        float v = acc[i][j][r] + bj[j];
        if (WF32)  Cf[(size_t)mr*N + nn] = v;
        if (WBF16) Cb[(size_t)mr*N + nn] = f2bf(v);
      }
    }
  }
}

// ---------------- hb [9600][4096] -> hbT [32][512][2400] (bf16) ----------------
__global__ __launch_bounds__(256) void k_hbt(const u16* __restrict__ hb, u16* __restrict__ hbT) {
  __shared__ u16 tile[64*33];
  int nt = blockIdx.x, ft = blockIdx.y, b = blockIdx.z, t = threadIdx.x;
  int n0 = nt*32, f0 = ft*64;
  int rrel = t >> 6, g = (t >> 3) & 7, fi = (t & 7)*8;
  const u16* src = hb + ((size_t)(b*300 + (n0 >> 3) + rrel))*4096 + g*512 + f0 + fi;
  u16 v[8];
  *(u16x4*)v = *(const u16x4*)src;
  *(u16x4*)(v+4) = *(const u16x4*)(src+4);
  int nl = rrel*8 + g;
#pragma unroll
  for (int e = 0; e < 8; e++) tile[(fi+e)*33 + nl] = v[e];
  __syncthreads();
  int f = t >> 2, nc = (t & 3)*8;
  u16 o[8];
#pragma unroll
  for (int e = 0; e < 8; e++) o[e] = tile[f*33 + nc + e];
  u16* dst = hbT + ((size_t)b*512 + f0 + f)*2400 + n0 + nc;
  *(u16x4*)dst = *(u16x4*)o;
  *(u16x4*)(dst+4) = *(u16x4*)(o+4);
}

// ---------------- bn1 + softmax(K=64) + att(from ext cols) -> actT bf16 [32][64][2400] ----------------
__global__ __launch_bounds__(512) void k_softmax(const float* __restrict__ act_ext,
    const float* __restrict__ fc2_b,
    const float* __restrict__ g, const float* __restrict__ b,
    const float* __restrict__ mu, const float* __restrict__ var, u16* __restrict__ actT) {
  int m = blockIdx.x, t = threadIdx.x;
  int bb = m / 300, fr = m - bb*300;
  int gi = t >> 6, k = t & 63, c = t;
  float v = act_ext[(size_t)m*640 + c];
  v = (v - mu[c]) * rsqrtf(var[c] + 1e-5f) * g[c] + b[c];
  float mx = v;
#pragma unroll
  for (int off = 32; off > 0; off >>= 1) mx = fmaxf(mx, __shfl_xor(mx, off, 64));
  float e = __expf(v - mx);
  float s = e;
#pragma unroll
  for (int off = 32; off > 0; off >>= 1) s += __shfl_xor(s, off, 64);
  float attl = act_ext[(size_t)m*640 + 512 + gi] + fc2_b[gi];
  float attv = 1.f / (1.f + __expf(-attl));
  float r = (e / s) * attv;
  __shared__ u16 st[64*9];
  st[k*9 + gi] = f2bf(r);
  __syncthreads();
  if (t < 64) {
    u16 o[8];
#pragma unroll
    for (int e2 = 0; e2 < 8; e2++) o[e2] = st[t*9 + e2];
    u16* dst = actT + ((size_t)bb*64 + t)*2400 + fr*8;
    *(u16x4*)dst = *(u16x4*)o;
    *(u16x4*)(dst+4) = *(u16x4*)(o+4);
  }
}

// ---------------- a_sum[b,k] = sum_n actT[b,k,n] ----------------
__global__ __launch_bounds__(256) void k_asum(const u16* __restrict__ actT, float* __restrict__ a_sum) {
  int b = blockIdx.x, t = threadIdx.x;
  int k = t >> 2, q = t & 3;
  const u16* p = actT + ((size_t)b*64 + k)*2400 + q*600;
  float acc = 0.f;
  for (int j = 0; j < 600; j += 8) {
    u16x4 a0 = *(const u16x4*)(p + j);
    u16x4 a1 = *(const u16x4*)(p + j + 4);
    acc += bf2f(a0[0])+bf2f(a0[1])+bf2f(a0[2])+bf2f(a0[3])
         + bf2f(a1[0])+bf2f(a1[1])+bf2f(a1[2])+bf2f(a1[3]);
  }
  __shared__ float red[256];
  red[t] = acc;
  __syncthreads();
  if (t < 64) a_sum[b*64 + t] = red[t*4] + red[t*4+1] + red[t*4+2] + red[t*4+3];
}

// ---------------- vlad MFMA: P2[ns][b][f][k] = sum_{n in chunk} hbT[b][f][n]*actT[b][k][n] ----------------
__global__ __launch_bounds__(256) void k_vlad(const u16* __restrict__ hbT, const u16* __restrict__ actT,
                                              float* __restrict__ P2) {
  __shared__ u16 As[128*32];
  __shared__ u16 Bs[64*32];
  int t = threadIdx.x, wv = t >> 6;
  int quad = (t & 63) >> 4, lr = t & 15;
  int ft = blockIdx.x, b = blockIdx.y, ns = blockIdx.z;
  int wm = wv & 1, wn = wv >> 1;
  int srow = t >> 2;
  int scol = (((t & 3) ^ ((t >> 3) & 3)) * 8);
  int xq = (quad ^ ((lr >> 1) & 3)) * 8;
  const u16* gA = hbT + ((size_t)b*512 + ft*128 + srow)*2400 + ns*480 + scol;
  const u16* gB = actT + ((size_t)b*64 + srow)*2400 + ns*480 + scol;
  u16* lA = &As[wv*512];
  u16* lB = &Bs[wv*512];
  f32x4 acc[4][2];
#pragma unroll
  for (int i = 0; i < 4; i++)
#pragma unroll
    for (int j = 0; j < 2; j++) acc[i][j] = (f32x4){0.f,0.f,0.f,0.f};
  for (int k0 = 0; k0 < 480; k0 += 32) {
    gl_lds16(gA + k0, lA);
    gl_lds16(gA + (size_t)64*2400 + k0, lA + 2048);
    gl_lds16(gB + k0, lB);
    __syncthreads();
    s16x8 af[4], bfr[2];
#pragma unroll
    for (int i = 0; i < 4; i++)
      af[i] = *(const s16x8*)&As[(wm*64 + i*16 + lr)*32 + xq];
#pragma unroll
    for (int j = 0; j < 2; j++)
      bfr[j] = *(const s16x8*)&Bs[(wn*32 + j*16 + lr)*32 + xq];
#pragma unroll
    for (int i = 0; i < 4; i++)
#pragma unroll
      for (int j = 0; j < 2; j++)
        acc[i][j] = __builtin_amdgcn_mfma_f32_16x16x32_bf16(af[i], bfr[j], acc[i][j], 0, 0, 0);
    __syncthreads();
  }
  size_t base = ((size_t)ns*32 + b)*512*64;
#pragma unroll
  for (int j = 0; j < 2; j++) {
    int kc = wn*32 + j*16 + lr;
#pragma unroll
    for (int i = 0; i < 4; i++) {
      int f = ft*128 + wm*64 + i*16 + quad*4;
#pragma unroll
      for (int r = 0; r < 4; r++)
        P2[base + (size_t)(f + r)*64 + kc] = acc[i][j][r];
    }
  }
}

// ---------------- sum partials, subtract a, intra-norm over f, bn2 -> vladn [32][32768] ----------------
__global__ __launch_bounds__(256) void k_norm2(const float* __restrict__ P2, const float* __restrict__ a_sum,
    const float* __restrict__ c2, const float* __restrict__ g, const float* __restrict__ b,
    const float* __restrict__ mu, const float* __restrict__ var, float* __restrict__ out) {
  int k = blockIdx.x, bb = blockIdx.y, t = threadIdx.x;
  float as = a_sum[bb*64 + k];
  int f0 = t, f1 = t + 256;
  const size_t PS = (size_t)32*512*64;
  size_t base = (size_t)bb*512*64;
  float x0 = 0.f, x1 = 0.f;
#pragma unroll
  for (int ns = 0; ns < 5; ns++) {
    x0 += P2[ns*PS + base + (size_t)f0*64 + k];
    x1 += P2[ns*PS + base + (size_t)f1*64 + k];
  }
  x0 -= as * c2[f0*64 + k];
  x1 -= as * c2[f1*64 + k];
  float s = x0*x0 + x1*x1;
#pragma unroll
  for (int off = 32; off > 0; off >>= 1) s += __shfl_xor(s, off, 64);
  __shared__ float red[4];
  if ((t & 63) == 0) red[t >> 6] = s;
  __syncthreads();
  float inv = 1.f / fmaxf(sqrtf(red[0]+red[1]+red[2]+red[3]), 1e-12f);
  int c0 = f0*64 + k, c1 = f1*64 + k;
  out[(size_t)bb*32768 + c0] = (x0*inv - mu[c0]) * rsqrtf(var[c0]+1e-5f) * g[c0] + b[c0];
  out[(size_t)bb*32768 + c1] = (x1*inv - mu[c1]) * rsqrtf(var[c1]+1e-5f) * g[c1] + b[c1];
}

// ---------------- split-K small-M MFMA GEMM ----------------
__global__ __launch_bounds__(256) void k_skgemm(
    const float* __restrict__ A, const float* __restrict__ W,
    float* __restrict__ P, int N, int K, int KC, int Npad) {
  constexpr int LDB = 72;
  __shared__ u16 Bs[128*LDB];
  __shared__ u16 As[32*LDB];
  int t = threadIdx.x;
  int wv = t >> 6, quad = (t & 63) >> 4, lr = t & 15;
  int n0 = blockIdx.x * 128;
  size_t kc0 = (size_t)blockIdx.y * KC;
  f32x4 acc[2][2];
#pragma unroll
  for (int i = 0; i < 2; i++)
#pragma unroll
    for (int j = 0; j < 2; j++) acc[i][j] = (f32x4){0.f,0.f,0.f,0.f};
  int wl[8]; size_t wg[8];
#pragma unroll
  for (int i = 0; i < 8; i++) {
    int slot = i*256 + t;
    int r = slot >> 4, q = slot & 15;
    int row = n0 + r; if (row >= N) row = N - 1;
    wl[i] = r*LDB + q*4;
    wg[i] = (size_t)row*K + kc0 + q*4;
  }
  int al[2]; size_t ag[2];
#pragma unroll
  for (int i = 0; i < 2; i++) {
    int slot = i*256 + t;
    int r = slot >> 4, q = slot & 15;
    al[i] = r*LDB + q*4;
    ag[i] = (size_t)r*K + kc0 + q*4;
  }
  int nst = KC >> 6;
  f32x4 wv4[8], av4[2];
#pragma unroll
  for (int i = 0; i < 8; i++) wv4[i] = *(const f32x4*)(W + wg[i]);
#pragma unroll
  for (int i = 0; i < 2; i++) av4[i] = *(const f32x4*)(A + ag[i]);
  for (int s = 0; s < nst; s++) {
    if (s) __syncthreads();
#pragma unroll
    for (int i = 0; i < 8; i++) {
      u16x4 o;
      o[0] = f2bf(wv4[i][0]); o[1] = f2bf(wv4[i][1]);
      o[2] = f2bf(wv4[i][2]); o[3] = f2bf(wv4[i][3]);
      *(u16x4*)&Bs[wl[i]] = o;
    }
#pragma unroll
    for (int i = 0; i < 2; i++) {
      u16x4 o;
      o[0] = f2bf(av4[i][0]); o[1] = f2bf(av4[i][1]);
      o[2] = f2bf(av4[i][2]); o[3] = f2bf(av4[i][3]);
      *(u16x4*)&As[al[i]] = o;
    }
    __syncthreads();
    if (s + 1 < nst) {
      int off = (s + 1) * 64;
#pragma unroll
      for (int i = 0; i < 8; i++) wv4[i] = *(const f32x4*)(W + wg[i] + off);
#pragma unroll
      for (int i = 0; i < 2; i++) av4[i] = *(const f32x4*)(A + ag[i] + off);
    }
#pragma unroll
    for (int ks = 0; ks < 2; ks++) {
      s16x8 af[2];
#pragma unroll
      for (int i = 0; i < 2; i++)
        af[i] = *(const s16x8*)&As[(i*16 + lr)*LDB + ks*32 + quad*8];
#pragma unroll
      for (int j = 0; j < 2; j++) {
        s16x8 bf = *(const s16x8*)&Bs[(wv*32 + j*16 + lr)*LDB + ks*32 + quad*8];
#pragma unroll
        for (int i = 0; i < 2; i++)
          acc[i][j] = __builtin_amdgcn_mfma_f32_16x16x32_bf16(af[i], bf, acc[i][j], 0, 0, 0);
      }
    }
  }
#pragma unroll
  for (int i = 0; i < 2; i++)
#pragma unroll
    for (int j = 0; j < 2; j++) {
      int n = n0 + wv*32 + j*16 + lr;
#pragma unroll
      for (int r = 0; r < 4; r++) {
        int m = i*16 + quad*4 + r;
        P[((size_t)blockIdx.y*32 + m)*Npad + n] = acc[i][j][r];
      }
    }
}

// ---------------- split-K reduce + epilogue ----------------
template<int EPI>
__global__ __launch_bounds__(256) void k_skred(const float* __restrict__ P, int KSPLIT, int N, int Npad,
    const float* __restrict__ bias, const float* __restrict__ bg, const float* __restrict__ bb,
    const float* __restrict__ bm, const float* __restrict__ bv, float* __restrict__ C) {
  int idx = blockIdx.x*256 + threadIdx.x;
  if (idx >= 32*N) return;
  int m = idx / N, n = idx - m*N;
  float s = 0.f;
  for (int k = 0; k < KSPLIT; k++) s += P[((size_t)k*32 + m)*Npad + n];
  float v = s + (bias ? bias[n] : 0.f);
  if (EPI == 1 || EPI == 2) {
    v = (v - bm[n]) * rsqrtf(bv[n] + 1e-5f) * bg[n] + bb[n];
    if (EPI == 2) v = fmaxf(v, 0.f);
  } else if (EPI == 3) {
    v = 1.f / (1.f + __expf(-v));
  }
  C[idx] = v;
}

// ---------------- elementwise multiply ----------------
__global__ void k_mul(const float* __restrict__ a, const float* __restrict__ b, float* __restrict__ o, int n) {
  int i = blockIdx.x*256 + threadIdx.x;
  if (i < n) o[i] = a[i]*b[i];
}

extern "C" void kernel_launch(void* const* d_in, const int* in_sizes, int n_in,
                              void* d_out, int out_size, void* d_ws, size_t ws_size,
                              hipStream_t stream) {
  (void)in_sizes; (void)n_in; (void)out_size; (void)ws_size;
  const float* x      = (const float*)d_in[0];
  const float* fc1_w  = (const float*)d_in[1];
  const float* fc1_b  = (const float*)d_in[2];
  const float* fc2_w  = (const float*)d_in[3];
  const float* fc2_b  = (const float*)d_in[4];
  const float* c1     = (const float*)d_in[5];
  const float* c2     = (const float*)d_in[6];
  const float* bn1_g  = (const float*)d_in[7];
  const float* bn1_b  = (const float*)d_in[8];
  const float* bn1_m  = (const float*)d_in[9];
  const float* bn1_v  = (const float*)d_in[10];
  const float* bn2_g  = (const float*)d_in[11];
  const float* bn2_b  = (const float*)d_in[12];
  const float* bn2_m  = (const float*)d_in[13];
  const float* bn2_v  = (const float*)d_in[14];
  const float* cgf_w  = (const float*)d_in[15];
  const float* cgf_b  = (const float*)d_in[16];
  const float* cgbn_g = (const float*)d_in[17];
  const float* cgbn_b = (const float*)d_in[18];
  const float* cgbn_m = (const float*)d_in[19];
  const float* cgbn_v = (const float*)d_in[20];
  const float* g1_w   = (const float*)d_in[21];
  const float* g1_b   = (const float*)d_in[22];
  const float* gbn_g  = (const float*)d_in[23];
  const float* gbn_b  = (const float*)d_in[24];
  const float* gbn_m  = (const float*)d_in[25];
  const float* gbn_v  = (const float*)d_in[26];
  const float* g2_w   = (const float*)d_in[27];
  const float* g2_b   = (const float*)d_in[28];
  const float* fc3_w  = (const float*)d_in[29];
  const float* fc3_b  = (const float*)d_in[30];

  char* w = (char*)d_ws;
  // region [0, 78643200): xn + w1b during phase 1; hbT after GEMM1
  u16*   xn    = (u16*)  (w + 0);                 // 39,321,600
  u16*   w1b   = (u16*)  (w + 39321600);          // 16,777,216
  u16*   hbT   = (u16*)  (w + 0);                 // 78,643,200 (after GEMM1)
  u16*   hb    = (u16*)  (w + 78643200);          // 78,643,200
  u16*   c1ext = (u16*)  (w + 157286400);         // 640*4096*2 = 5,242,880
  float* actx  = (float*)(w + 162529280);         // 9600*640*4 = 24,576,000
  u16*   actT  = (u16*)  (w + 187105280);         // 32*64*2400*2 = 9,830,400
  float* P2    = (float*)(w + 196935680);         // 5*32*512*64*4 = 20,971,520
  float* P     = (float*)(w + 196935680);         // skgemm partials reuse P2 region
  float* a_sum = (float*)(w + 217907200);         // 8,192
  float* vladn = (float*)(w + 217915392);         // 4,194,304
  float* y     = (float*)(w + 222109696);         // 262,144
  float* z     = (float*)(w + 222371840);         // 32,768
  float* gate  = (float*)(w + 222404608);         // 262,144
  float* yg    = (float*)(w + 222666752);         // 262,144
  // total ~222.9 MB

  k_l2norm<<<9600, 256, 0, stream>>>(x, xn);
  k_cvt<<<2048, 256, 0, stream>>>(fc1_w, w1b, (4096*2048)/4);
  k_transpose<<<dim3(128, 16), 256, 0, stream>>>(c1, c1ext);
  k_cvt<<<32, 256, 0, stream>>>(fc2_w, c1ext + (size_t)512*4096, (8*4096)/4);
  // GEMM1: h = xn @ fc1_w.T + fc1_b -> bf16 [9600][4096]; 256^2 pipelined kernel.
  // MT=38 (tail tile rows 9472..9727 read into w1b region - allocated, garbage
  // guarded at store), NT=16, grid 608, swz=2 (XCD supertile 19x4).
  k_gemm256<false, true><<<608, 512, 0, stream>>>(xn, w1b, fc1_b, nullptr, hb,
                                                  9600, 4096, 2048, 4096, 38, 16, 2);
  // hb -> hbT [32][512][2400] (overwrites xn/w1b)
  k_hbt<<<dim3(75, 8, 32), 256, 0, stream>>>(hb, hbT);
  // GEMM2+att: act_ext = h @ [c1 | fc2_w].T -> f32 [9600][640] (store cols < 520)
  k_gemm<true, false><<<375, 256, 0, stream>>>(hb, c1ext, nullptr, actx, nullptr, 640, 4096, 520, 75, 5, 0);
  // bn1 + softmax + att -> actT bf16 [32][64][2400]
  k_softmax<<<9600, 512, 0, stream>>>(actx, fc2_b, bn1_g, bn1_b, bn1_m, bn1_v, actT);
  k_asum<<<32, 256, 0, stream>>>(actT, a_sum);
  // vlad partials
  k_vlad<<<dim3(4, 32, 5), 256, 0, stream>>>(hbT, actT, P2);
  k_norm2<<<dim3(64, 32), 256, 0, stream>>>(P2, a_sum, c2, bn2_g, bn2_b, bn2_m, bn2_v, vladn);

  // cgf: y = BN(vladn @ cgf_w.T + cgf_b)   N=2048, K=32768, KSPLIT=64, KC=512
  k_skgemm<<<dim3(16, 64), 256, 0, stream>>>(vladn, cgf_w, P, 2048, 32768, 512, 2048);
  k_skred<1><<<256, 256, 0, stream>>>(P, 64, 2048, 2048, cgf_b, cgbn_g, cgbn_b, cgbn_m, cgbn_v, y);
  // g1: z = relu(BN(y @ g1_w.T + g1_b))    N=256, K=2048, KSPLIT=32, KC=64
  k_skgemm<<<dim3(2, 32), 256, 0, stream>>>(y, g1_w, P, 256, 2048, 64, 256);
  k_skred<2><<<32, 256, 0, stream>>>(P, 32, 256, 256, g1_b, gbn_g, gbn_b, gbn_m, gbn_v, z);
  // g2: gate = sigmoid(z @ g2_w.T + g2_b)  N=2048, K=256, KSPLIT=4, KC=64
  k_skgemm<<<dim3(16, 4), 256, 0, stream>>>(z, g2_w, P, 2048, 256, 64, 2048);
  k_skred<3><<<256, 256, 0, stream>>>(P, 4, 2048, 2048, g2_b, nullptr, nullptr, nullptr, nullptr, gate);
  k_mul<<<256, 256, 0, stream>>>(y, gate, yg, 65536);
  // fc3: out = yg @ fc3_w.T + fc3_b        N=3862 (pad 3968), K=2048, KSPLIT=16, KC=128
  k_skgemm<<<dim3(31, 16), 256, 0, stream>>>(yg, fc3_w, P, 3862, 2048, 128, 3968);
  k_skred<0><<<483, 256, 0, stream>>>(P, 16, 3862, 3968, fc3_b, nullptr, nullptr, nullptr, nullptr, (float*)d_out);
}

// Round 3
// 994.437 us; speedup vs baseline: 1.0266x; 1.0089x over previous
//
#include <hip/hip_runtime.h>

typedef unsigned short u16;
typedef unsigned int u32;
using f32x4 = __attribute__((ext_vector_type(4))) float;
using s16x8 = __attribute__((ext_vector_type(8))) short;
using u16x4 = __attribute__((ext_vector_type(4))) u16;

#define DEV __device__ __forceinline__

DEV float bf2f(u16 u) { union { u32 i; float f; } v; v.i = ((u32)u) << 16; return v.f; }
DEV u16 f2bf(float f) {
  union { float ff; u32 uu; } v; v.ff = f;
  u32 r = (v.uu + 0x7fffu + ((v.uu >> 16) & 1u)) >> 16;
  return (u16)r;
}

DEV void gl_lds16(const void* g, void* l) {
  __builtin_amdgcn_global_load_lds(
      (const __attribute__((address_space(1))) u32*)g,
      (__attribute__((address_space(3))) u32*)l, 16, 0, 0);
}

DEV void BAR() { __builtin_amdgcn_s_barrier(); __builtin_amdgcn_sched_barrier(0); }
DEV void VM6() { asm volatile("s_waitcnt vmcnt(6)" ::: "memory"); }
DEV void VM0() { asm volatile("s_waitcnt vmcnt(0)" ::: "memory"); }
DEV void PRIO1() { __builtin_amdgcn_s_setprio(1); }
DEV void PRIO0() { __builtin_amdgcn_s_setprio(0); }

// inline-asm ds_read_b128: invisible to the compiler's LDS<->global_load_lds
// aliasing model, so no conservative vmem drains get inserted before it.
#define DSR(d, a, OFF) asm volatile("ds_read_b128 %0, %1 offset:" #OFF \
                                    : "=&v"(d) : "v"(a))
// B-first issue order so the first MFMA group's operands land earliest.
#define READ12B(aa, bb) do {                                                   \
  unsigned a_ = (aa), b_ = (bb);                                               \
  DSR(fb[0], b_, 0);     DSR(fb[1], b_, 2048);                                 \
  DSR(fb[2], b_, 4096);  DSR(fb[3], b_, 6144);                                 \
  DSR(fa[0], a_, 0);     DSR(fa[1], a_, 2048);                                 \
  DSR(fa[2], a_, 4096);  DSR(fa[3], a_, 6144);                                 \
  DSR(fa[4], a_, 8192);  DSR(fa[5], a_, 10240);                                \
  DSR(fa[6], a_, 12288); DSR(fa[7], a_, 14336);                                \
} while (0)

// Counted-lgkmcnt MFMA group: DS ops complete in order per wave, so after
// issuing 12 reads (4 B + 8 A), lgkmcnt(7-i) guarantees fb[0..3] and fa[0..i]
// have landed. sched_barrier(0) stops MFMA hoisting above the wait (rule #18);
// any reads hoisted between groups by the scheduler only make waits stricter.
#define GRP4(I_, N_) do {                                                      \
  asm volatile("s_waitcnt lgkmcnt(" #N_ ")" ::: "memory");                     \
  __builtin_amdgcn_sched_barrier(0);                                           \
  acc[I_][0] = __builtin_amdgcn_mfma_f32_16x16x32_bf16(fa[I_], fb[0], acc[I_][0], 0, 0, 0); \
  acc[I_][1] = __builtin_amdgcn_mfma_f32_16x16x32_bf16(fa[I_], fb[1], acc[I_][1], 0, 0, 0); \
  acc[I_][2] = __builtin_amdgcn_mfma_f32_16x16x32_bf16(fa[I_], fb[2], acc[I_][2], 0, 0, 0); \
  acc[I_][3] = __builtin_amdgcn_mfma_f32_16x16x32_bf16(fa[I_], fb[3], acc[I_][3], 0, 0, 0); \
} while (0)

#define PHASE32() do {                                                         \
  PRIO1();                                                                     \
  GRP4(0,7); GRP4(1,6); GRP4(2,5); GRP4(3,4);                                  \
  GRP4(4,3); GRP4(5,2); GRP4(6,1); GRP4(7,0);                                  \
  PRIO0();                                                                     \
} while (0)

// ---------------- L2 normalize per frame, emit bf16 ----------------
__global__ __launch_bounds__(256) void k_l2norm(const float* __restrict__ x, u16* __restrict__ xn) {
  int r = blockIdx.x, t = threadIdx.x;
  const float* xr = x + (size_t)r * 2048;
  float v[8], s = 0.f;
#pragma unroll
  for (int i = 0; i < 8; i++) { v[i] = xr[t + i*256]; s += v[i]*v[i]; }
#pragma unroll
  for (int off = 32; off > 0; off >>= 1) s += __shfl_xor(s, off, 64);
  __shared__ float red[4];
  if ((t & 63) == 0) red[t >> 6] = s;
  __syncthreads();
  float inv = 1.f / fmaxf(sqrtf(red[0]+red[1]+red[2]+red[3]), 1e-12f);
  u16* xo = xn + (size_t)r * 2048;
#pragma unroll
  for (int i = 0; i < 8; i++) xo[t + i*256] = f2bf(v[i]*inv);
}

// ---------------- f32 -> bf16 ----------------
__global__ void k_cvt(const float* __restrict__ in, u16* __restrict__ out, int n4) {
  int i = blockIdx.x*256 + threadIdx.x, st = gridDim.x*256;
  for (; i < n4; i += st) {
    f32x4 v = ((const f32x4*)in)[i];
    u16x4 o;
    o[0] = f2bf(v[0]); o[1] = f2bf(v[1]); o[2] = f2bf(v[2]); o[3] = f2bf(v[3]);
    ((u16x4*)out)[i] = o;
  }
}

// ---------------- c1 [4096][512] -> c1ext bf16 rows 0..511 [640][4096] ----------------
__global__ __launch_bounds__(256) void k_transpose(const float* __restrict__ c1, u16* __restrict__ c1t) {
  __shared__ float tile[32][33];
  int k0 = blockIdx.x*32, n0 = blockIdx.y*32;
  int tx = threadIdx.x & 31, ty = threadIdx.x >> 5;
  for (int i = ty; i < 32; i += 8) tile[i][tx] = c1[(size_t)(k0+i)*512 + n0 + tx];
  __syncthreads();
  for (int i = ty; i < 32; i += 8) c1t[(size_t)(n0+i)*4096 + k0 + tx] = f2bf(tile[tx][i]);
}

// ---------------- bf16 MFMA NT GEMM, 128x128 tile (kept for GEMM2) ----------------
template<bool WF32, bool WBF16>
__global__ __launch_bounds__(256) void k_gemm(
    const u16* __restrict__ A, const u16* __restrict__ Bt, const float* __restrict__ bias,
    float* __restrict__ Cf, u16* __restrict__ Cb, int N, int K, int Nlim,
    int MT, int NT, int swz) {
  __shared__ u16 As[128*32];
  __shared__ u16 Bs[128*32];
  int bid = blockIdx.x, mt, nt;
  if (swz) {
    int mg = (MT + 7) >> 3;
    int gid = bid >> 5, gl = bid & 31;
    mt = (gid % mg)*8 + (gl & 7);
    nt = (gid / mg)*4 + (gl >> 3);
    if (mt >= MT) return;
  } else { mt = bid % MT; nt = bid / MT; }
  int t = threadIdx.x, wv = t >> 6;
  int quad = (t & 63) >> 4, lr = t & 15;
  size_t m0 = (size_t)mt * 128, n0 = (size_t)nt * 128;
  int wm = wv & 1, wn = wv >> 1;
  int srow = t >> 2;
  int scol = (((t & 3) ^ ((t >> 3) & 3)) * 8);   // XOR-swizzled k-chunk
  const u16* gA = A + (m0 + srow)*(size_t)K + scol;
  const u16* gB = Bt + (n0 + srow)*(size_t)K + scol;
  u16* lA = &As[wv*512];
  u16* lB = &Bs[wv*512];
  int xq = (quad ^ ((lr >> 1) & 3)) * 8;          // matching frag-read chunk
  f32x4 acc[4][4];
#pragma unroll
  for (int i = 0; i < 4; i++)
#pragma unroll
    for (int j = 0; j < 4; j++) acc[i][j] = (f32x4){0.f,0.f,0.f,0.f};
  for (int k0 = 0; k0 < K; k0 += 32) {
    gl_lds16(gA + k0, lA);
    gl_lds16(gA + (size_t)64*K + k0, lA + 2048);
    gl_lds16(gB + k0, lB);
    gl_lds16(gB + (size_t)64*K + k0, lB + 2048);
    __syncthreads();
    s16x8 af[4], bfr[4];
#pragma unroll
    for (int i = 0; i < 4; i++) {
      af[i]  = *(const s16x8*)&As[(wm*64 + i*16 + lr)*32 + xq];
      bfr[i] = *(const s16x8*)&Bs[(wn*64 + i*16 + lr)*32 + xq];
    }
#pragma unroll
    for (int i = 0; i < 4; i++)
#pragma unroll
      for (int j = 0; j < 4; j++)
        acc[i][j] = __builtin_amdgcn_mfma_f32_16x16x32_bf16(af[i], bfr[j], acc[i][j], 0, 0, 0);
    __syncthreads();
  }
#pragma unroll
  for (int j = 0; j < 4; j++) {
    size_t nn = n0 + wn*64 + j*16 + lr;
    if ((int)nn >= Nlim) continue;
    float bj = bias ? bias[nn] : 0.f;
#pragma unroll
    for (int i = 0; i < 4; i++) {
      size_t mr = m0 + wm*64 + i*16 + quad*4;
#pragma unroll
      for (int r = 0; r < 4; r++) {
        float v = acc[i][j][r] + bj;
        if (WF32)  Cf[(mr + r)*N + nn] = v;
        if (WBF16) Cb[(mr + r)*N + nn] = f2bf(v);
      }
    }
  }
}

// ---------------- 256x256 bf16 MFMA GEMM, counted-lgkm interleaved pipeline ----------------
// C[m,n] = sum_k A[m,k]*Bt[n,k] (+bias). 512 threads = 8 waves (2M x 4N),
// double-buffered 128 KiB LDS, counted vmcnt(6) keeps staging loads in flight
// across barriers; per K-slice: 12 asm ds_read_b128 issued B-first, then 8
// groups of {lgkmcnt(7-i); sched_barrier; 4 MFMA} so LDS reads overlap MFMA.
// 2 barriers per K-tile: (1) after both slices read -> cur buffer stageable,
// (2) after VM6 -> next buffer resident chip-wide.
// LDS chunk swizzle (both-sides): logical 16B chunk c of row r at phys c^(r&7),
// via pre-swizzled global source + XOR'd read addresses.
// swz==2: bijective XCD supertile map (19mt x 4nt per XCD; needs MT=38,NT=16).
template<bool WF32, bool WBF16>
__global__ __launch_bounds__(512, 2) void k_gemm256(
    const u16* __restrict__ A, const u16* __restrict__ Bt, const float* __restrict__ bias,
    float* __restrict__ Cf, u16* __restrict__ Cb,
    int M, int N, int K, int Nlim, int MT, int NT, int swz) {
  constexpr int TILE = 256*64;                 // u16 elems per matrix per buffer
  __shared__ u16 lds[4*TILE];                  // A0|B0|A1|B1, 32 KiB each
  int bid = blockIdx.x, mt, nt;
  if (swz == 2) {
    // one 19mt x 4nt supertile per XCD (grid 608 = 8*76, bijective)
    int x = bid & 7, w2 = bid >> 3;
    mt = (x & 1)*19 + w2 % 19;
    nt = (x >> 1)*4 + w2 / 19;
  } else if (swz == 1) {
    int c = (MT*NT) >> 3; int b2 = (bid & 7)*c + (bid >> 3);
    mt = b2 % MT; nt = b2 / MT;
  } else { mt = bid % MT; nt = bid / MT; }
  int t = threadIdx.x, wv = t >> 6, lane = t & 63;
  int quad = lane >> 4, lr = lane & 15;
  int wm = wv >> 2, wn = wv & 3;               // 2M x 4N waves
  size_t m0 = (size_t)mt * 256, n0 = (size_t)nt * 256;
  // staging: lane l covers (row 8*wv + (l>>3), phys chunk l&7); source chunk pre-swizzled
  int srow = wv*8 + (lane >> 3);
  int schunk = ((lane & 7) ^ (lane >> 3)) * 8;
  const u16* gA = A  + (size_t)(m0 + srow)*K + schunk;
  const u16* gB = Bt + (size_t)(n0 + srow)*K + schunk;
  size_t row64 = (size_t)64 * K;
  int lofs = wv*512;                           // wave's 1KiB slot per 64-row group
  // fragment read addresses (bytes); slice1 = ^64, buffer flip = ^0x10000
  unsigned ldsB = (unsigned)(size_t)lds;
  unsigned pc = (unsigned)((quad ^ (lr & 7)) << 4);
  unsigned aCur = ldsB + (unsigned)((wm*128 + lr)*128) + pc;
  unsigned bCur = ldsB + 32768u + (unsigned)((wn*64 + lr)*128) + pc;
  f32x4 acc[8][4];
#pragma unroll
  for (int i = 0; i < 8; i++)
#pragma unroll
    for (int j = 0; j < 4; j++) acc[i][j] = (f32x4){0.f,0.f,0.f,0.f};

  int T = K >> 6;
  u16* A0 = lds;            u16* B0 = lds + TILE;
  u16* A1 = lds + 2*TILE;   u16* B1 = lds + 3*TILE;
  // ---- prologue: tile0 full (8) + tile1 trio (6) ----
#pragma unroll
  for (int q = 0; q < 4; q++) gl_lds16(gA + q*row64, A0 + q*4096 + lofs);
#pragma unroll
  for (int q = 0; q < 4; q++) gl_lds16(gB + q*row64, B0 + q*4096 + lofs);
#pragma unroll
  for (int q = 0; q < 4; q++) gl_lds16(gA + 64 + q*row64, A1 + q*4096 + lofs);
  gl_lds16(gB + 64,          B1 + lofs);
  gl_lds16(gB + 64 + row64,  B1 + 4096 + lofs);
  VM6();          // tile0 resident; tile1 trio stays in flight
  BAR();

  s16x8 fa[8], fb[4];
  for (int tt = 0; tt < T; ++tt) {
    // ---- slice0: issue reads, issue Bh1(tt+1), interleaved wait/MFMA ----
    READ12B(aCur, bCur);
    if (tt + 1 < T) {
      const u16* gB1 = gB + (size_t)(tt + 1)*64;
      u16* Bq = lds + (((tt + 1) & 1)*2 + 1)*TILE;
      gl_lds16(gB1 + 2*row64, Bq + 2*4096 + lofs);
      gl_lds16(gB1 + 3*row64, Bq + 3*4096 + lofs);
    }
    PHASE32();
    // ---- slice1: issue reads, interleaved wait/MFMA (no barrier between slices:
    //      both read the same resident buffer; no LDS writes intervene) ----
    READ12B(aCur ^ 64u, bCur ^ 64u);
    PHASE32();
    BAR();                     // all waves done reading buffer P -> P stageable
    if (tt + 2 < T) {
      const u16* gA2 = gA + (size_t)(tt + 2)*64;
      const u16* gB2 = gB + (size_t)(tt + 2)*64;
      u16* Ap = lds + ((tt & 1)*2)*TILE;
      u16* Bp = Ap + TILE;
#pragma unroll
      for (int q = 0; q < 4; q++) gl_lds16(gA2 + q*row64, Ap + q*4096 + lofs);
      gl_lds16(gB2,         Bp + lofs);
      gl_lds16(gB2 + row64, Bp + 4096 + lofs);
      VM6();                   // tile tt+1 fully landed; trio(tt+2) in flight
    } else if (tt + 1 < T) {
      VM0();                   // tail: drain for final tile
    }
    if (tt + 1 < T) BAR();     // residency barrier before reading buffer Q
    aCur ^= 0x10000u; bCur ^= 0x10000u;
  }

  // ---- epilogue (row-contiguous store order: i,r outer, j inner) ----
  float bj[4];
#pragma unroll
  for (int j = 0; j < 4; j++) {
    int nn = (int)n0 + wn*64 + j*16 + lr;
    bj[j] = (bias && nn < Nlim) ? bias[nn] : 0.f;
  }
#pragma unroll
  for (int i = 0; i < 8; i++) {
    int mrb = (int)m0 + wm*128 + i*16 + quad*4;
#pragma unroll
    for (int r = 0; r < 4; r++) {
      int mr = mrb + r;
      if (mr >= M) continue;
#pragma unroll
      for (int j = 0; j < 4; j++) {
        int nn = (int)n0 + wn*64 + j*16 + lr;
        if (nn >= Nlim) continue;
        float v = acc[i][j][r] + bj[j];
        if (WF32)  Cf[(size_t)mr*N + nn] = v;
        if (WBF16) Cb[(size_t)mr*N + nn] = f2bf(v);
      }
    }
  }
}

// ---------------- hb [9600][4096] -> hbT [32][512][2400] (bf16) ----------------
__global__ __launch_bounds__(256) void k_hbt(const u16* __restrict__ hb, u16* __restrict__ hbT) {
  __shared__ u16 tile[64*33];
  int nt = blockIdx.x, ft = blockIdx.y, b = blockIdx.z, t = threadIdx.x;
  int n0 = nt*32, f0 = ft*64;
  int rrel = t >> 6, g = (t >> 3) & 7, fi = (t & 7)*8;
  const u16* src = hb + ((size_t)(b*300 + (n0 >> 3) + rrel))*4096 + g*512 + f0 + fi;
  u16 v[8];
  *(u16x4*)v = *(const u16x4*)src;
  *(u16x4*)(v+4) = *(const u16x4*)(src+4);
  int nl = rrel*8 + g;
#pragma unroll
  for (int e = 0; e < 8; e++) tile[(fi+e)*33 + nl] = v[e];
  __syncthreads();
  int f = t >> 2, nc = (t & 3)*8;
  u16 o[8];
#pragma unroll
  for (int e = 0; e < 8; e++) o[e] = tile[f*33 + nc + e];
  u16* dst = hbT + ((size_t)b*512 + f0 + f)*2400 + n0 + nc;
  *(u16x4*)dst = *(u16x4*)o;
  *(u16x4*)(dst+4) = *(u16x4*)(o+4);
}

// ---------------- bn1 + softmax(K=64) + att(from ext cols) -> actT bf16 [32][64][2400] ----------------
__global__ __launch_bounds__(512) void k_softmax(const float* __restrict__ act_ext,
    const float* __restrict__ fc2_b,
    const float* __restrict__ g, const float* __restrict__ b,
    const float* __restrict__ mu, const float* __restrict__ var, u16* __restrict__ actT) {
  int m = blockIdx.x, t = threadIdx.x;
  int bb = m / 300, fr = m - bb*300;
  int gi = t >> 6, k = t & 63, c = t;
  float v = act_ext[(size_t)m*640 + c];
  v = (v - mu[c]) * rsqrtf(var[c] + 1e-5f) * g[c] + b[c];
  float mx = v;
#pragma unroll
  for (int off = 32; off > 0; off >>= 1) mx = fmaxf(mx, __shfl_xor(mx, off, 64));
  float e = __expf(v - mx);
  float s = e;
#pragma unroll
  for (int off = 32; off > 0; off >>= 1) s += __shfl_xor(s, off, 64);
  float attl = act_ext[(size_t)m*640 + 512 + gi] + fc2_b[gi];
  float attv = 1.f / (1.f + __expf(-attl));
  float r = (e / s) * attv;
  __shared__ u16 st[64*9];
  st[k*9 + gi] = f2bf(r);
  __syncthreads();
  if (t < 64) {
    u16 o[8];
#pragma unroll
    for (int e2 = 0; e2 < 8; e2++) o[e2] = st[t*9 + e2];
    u16* dst = actT + ((size_t)bb*64 + t)*2400 + fr*8;
    *(u16x4*)dst = *(u16x4*)o;
    *(u16x4*)(dst+4) = *(u16x4*)(o+4);
  }
}

// ---------------- a_sum[b,k] = sum_n actT[b,k,n] ----------------
__global__ __launch_bounds__(256) void k_asum(const u16* __restrict__ actT, float* __restrict__ a_sum) {
  int b = blockIdx.x, t = threadIdx.x;
  int k = t >> 2, q = t & 3;
  const u16* p = actT + ((size_t)b*64 + k)*2400 + q*600;
  float acc = 0.f;
  for (int j = 0; j < 600; j += 8) {
    u16x4 a0 = *(const u16x4*)(p + j);
    u16x4 a1 = *(const u16x4*)(p + j + 4);
    acc += bf2f(a0[0])+bf2f(a0[1])+bf2f(a0[2])+bf2f(a0[3])
         + bf2f(a1[0])+bf2f(a1[1])+bf2f(a1[2])+bf2f(a1[3]);
  }
  __shared__ float red[256];
  red[t] = acc;
  __syncthreads();
  if (t < 64) a_sum[b*64 + t] = red[t*4] + red[t*4+1] + red[t*4+2] + red[t*4+3];
}

// ---------------- vlad MFMA: P2[ns][b][f][k] = sum_{n in chunk} hbT[b][f][n]*actT[b][k][n] ----------------
__global__ __launch_bounds__(256) void k_vlad(const u16* __restrict__ hbT, const u16* __restrict__ actT,
                                              float* __restrict__ P2) {
  __shared__ u16 As[128*32];
  __shared__ u16 Bs[64*32];
  int t = threadIdx.x, wv = t >> 6;
  int quad = (t & 63) >> 4, lr = t & 15;
  int ft = blockIdx.x, b = blockIdx.y, ns = blockIdx.z;
  int wm = wv & 1, wn = wv >> 1;
  int srow = t >> 2;
  int scol = (((t & 3) ^ ((t >> 3) & 3)) * 8);
  int xq = (quad ^ ((lr >> 1) & 3)) * 8;
  const u16* gA = hbT + ((size_t)b*512 + ft*128 + srow)*2400 + ns*480 + scol;
  const u16* gB = actT + ((size_t)b*64 + srow)*2400 + ns*480 + scol;
  u16* lA = &As[wv*512];
  u16* lB = &Bs[wv*512];
  f32x4 acc[4][2];
#pragma unroll
  for (int i = 0; i < 4; i++)
#pragma unroll
    for (int j = 0; j < 2; j++) acc[i][j] = (f32x4){0.f,0.f,0.f,0.f};
  for (int k0 = 0; k0 < 480; k0 += 32) {
    gl_lds16(gA + k0, lA);
    gl_lds16(gA + (size_t)64*2400 + k0, lA + 2048);
    gl_lds16(gB + k0, lB);
    __syncthreads();
    s16x8 af[4], bfr[2];
#pragma unroll
    for (int i = 0; i < 4; i++)
      af[i] = *(const s16x8*)&As[(wm*64 + i*16 + lr)*32 + xq];
#pragma unroll
    for (int j = 0; j < 2; j++)
      bfr[j] = *(const s16x8*)&Bs[(wn*32 + j*16 + lr)*32 + xq];
#pragma unroll
    for (int i = 0; i < 4; i++)
#pragma unroll
      for (int j = 0; j < 2; j++)
        acc[i][j] = __builtin_amdgcn_mfma_f32_16x16x32_bf16(af[i], bfr[j], acc[i][j], 0, 0, 0);
    __syncthreads();
  }
  size_t base = ((size_t)ns*32 + b)*512*64;
#pragma unroll
  for (int j = 0; j < 2; j++) {
    int kc = wn*32 + j*16 + lr;
#pragma unroll
    for (int i = 0; i < 4; i++) {
      int f = ft*128 + wm*64 + i*16 + quad*4;
#pragma unroll
      for (int r = 0; r < 4; r++)
        P2[base + (size_t)(f + r)*64 + kc] = acc[i][j][r];
    }
  }
}

// ---------------- sum partials, subtract a, intra-norm over f, bn2 -> vladn [32][32768] ----------------
__global__ __launch_bounds__(256) void k_norm2(const float* __restrict__ P2, const float* __restrict__ a_sum,
    const float* __restrict__ c2, const float* __restrict__ g, const float* __restrict__ b,
    const float* __restrict__ mu, const float* __restrict__ var, float* __restrict__ out) {
  int k = blockIdx.x, bb = blockIdx.y, t = threadIdx.x;
  float as = a_sum[bb*64 + k];
  int f0 = t, f1 = t + 256;
  const size_t PS = (size_t)32*512*64;
  size_t base = (size_t)bb*512*64;
  float x0 = 0.f, x1 = 0.f;
#pragma unroll
  for (int ns = 0; ns < 5; ns++) {
    x0 += P2[ns*PS + base + (size_t)f0*64 + k];
    x1 += P2[ns*PS + base + (size_t)f1*64 + k];
  }
  x0 -= as * c2[f0*64 + k];
  x1 -= as * c2[f1*64 + k];
  float s = x0*x0 + x1*x1;
#pragma unroll
  for (int off = 32; off > 0; off >>= 1) s += __shfl_xor(s, off, 64);
  __shared__ float red[4];
  if ((t & 63) == 0) red[t >> 6] = s;
  __syncthreads();
  float inv = 1.f / fmaxf(sqrtf(red[0]+red[1]+red[2]+red[3]), 1e-12f);
  int c0 = f0*64 + k, c1 = f1*64 + k;
  out[(size_t)bb*32768 + c0] = (x0*inv - mu[c0]) * rsqrtf(var[c0]+1e-5f) * g[c0] + b[c0];
  out[(size_t)bb*32768 + c1] = (x1*inv - mu[c1]) * rsqrtf(var[c1]+1e-5f) * g[c1] + b[c1];
}

// ---------------- split-K small-M MFMA GEMM ----------------
__global__ __launch_bounds__(256) void k_skgemm(
    const float* __restrict__ A, const float* __restrict__ W,
    float* __restrict__ P, int N, int K, int KC, int Npad) {
  constexpr int LDB = 72;
  __shared__ u16 Bs[128*LDB];
  __shared__ u16 As[32*LDB];
  int t = threadIdx.x;
  int wv = t >> 6, quad = (t & 63) >> 4, lr = t & 15;
  int n0 = blockIdx.x * 128;
  size_t kc0 = (size_t)blockIdx.y * KC;
  f32x4 acc[2][2];
#pragma unroll
  for (int i = 0; i < 2; i++)
#pragma unroll
    for (int j = 0; j < 2; j++) acc[i][j] = (f32x4){0.f,0.f,0.f,0.f};
  int wl[8]; size_t wg[8];
#pragma unroll
  for (int i = 0; i < 8; i++) {
    int slot = i*256 + t;
    int r = slot >> 4, q = slot & 15;
    int row = n0 + r; if (row >= N) row = N - 1;
    wl[i] = r*LDB + q*4;
    wg[i] = (size_t)row*K + kc0 + q*4;
  }
  int al[2]; size_t ag[2];
#pragma unroll
  for (int i = 0; i < 2; i++) {
    int slot = i*256 + t;
    int r = slot >> 4, q = slot & 15;
    al[i] = r*LDB + q*4;
    ag[i] = (size_t)r*K + kc0 + q*4;
  }
  int nst = KC >> 6;
  f32x4 wv4[8], av4[2];
#pragma unroll
  for (int i = 0; i < 8; i++) wv4[i] = *(const f32x4*)(W + wg[i]);
#pragma unroll
  for (int i = 0; i < 2; i++) av4[i] = *(const f32x4*)(A + ag[i]);
  for (int s = 0; s < nst; s++) {
    if (s) __syncthreads();
#pragma unroll
    for (int i = 0; i < 8; i++) {
      u16x4 o;
      o[0] = f2bf(wv4[i][0]); o[1] = f2bf(wv4[i][1]);
      o[2] = f2bf(wv4[i][2]); o[3] = f2bf(wv4[i][3]);
      *(u16x4*)&Bs[wl[i]] = o;
    }
#pragma unroll
    for (int i = 0; i < 2; i++) {
      u16x4 o;
      o[0] = f2bf(av4[i][0]); o[1] = f2bf(av4[i][1]);
      o[2] = f2bf(av4[i][2]); o[3] = f2bf(av4[i][3]);
      *(u16x4*)&As[al[i]] = o;
    }
    __syncthreads();
    if (s + 1 < nst) {
      int off = (s + 1) * 64;
#pragma unroll
      for (int i = 0; i < 8; i++) wv4[i] = *(const f32x4*)(W + wg[i] + off);
#pragma unroll
      for (int i = 0; i < 2; i++) av4[i] = *(const f32x4*)(A + ag[i] + off);
    }
#pragma unroll
    for (int ks = 0; ks < 2; ks++) {
      s16x8 af[2];
#pragma unroll
      for (int i = 0; i < 2; i++)
        af[i] = *(const s16x8*)&As[(i*16 + lr)*LDB + ks*32 + quad*8];
#pragma unroll
      for (int j = 0; j < 2; j++) {
        s16x8 bf = *(const s16x8*)&Bs[(wv*32 + j*16 + lr)*LDB + ks*32 + quad*8];
#pragma unroll
        for (int i = 0; i < 2; i++)
          acc[i][j] = __builtin_amdgcn_mfma_f32_16x16x32_bf16(af[i], bf, acc[i][j], 0, 0, 0);
      }
    }
  }
#pragma unroll
  for (int i = 0; i < 2; i++)
#pragma unroll
    for (int j = 0; j < 2; j++) {
      int n = n0 + wv*32 + j*16 + lr;
#pragma unroll
      for (int r = 0; r < 4; r++) {
        int m = i*16 + quad*4 + r;
        P[((size_t)blockIdx.y*32 + m)*Npad + n] = acc[i][j][r];
      }
    }
}

// ---------------- split-K reduce + epilogue ----------------
template<int EPI>
__global__ __launch_bounds__(256) void k_skred(const float* __restrict__ P, int KSPLIT, int N, int Npad,
    const float* __restrict__ bias, const float* __restrict__ bg, const float* __restrict__ bb,
    const float* __restrict__ bm, const float* __restrict__ bv, float* __restrict__ C) {
  int idx = blockIdx.x*256 + threadIdx.x;
  if (idx >= 32*N) return;
  int m = idx / N, n = idx - m*N;
  float s = 0.f;
  for (int k = 0; k < KSPLIT; k++) s += P[((size_t)k*32 + m)*Npad + n];
  float v = s + (bias ? bias[n] : 0.f);
  if (EPI == 1 || EPI == 2) {
    v = (v - bm[n]) * rsqrtf(bv[n] + 1e-5f) * bg[n] + bb[n];
    if (EPI == 2) v = fmaxf(v, 0.f);
  } else if (EPI == 3) {
    v = 1.f / (1.f + __expf(-v));
  }
  C[idx] = v;
}

// ---------------- elementwise multiply ----------------
__global__ void k_mul(const float* __restrict__ a, const float* __restrict__ b, float* __restrict__ o, int n) {
  int i = blockIdx.x*256 + threadIdx.x;
  if (i < n) o[i] = a[i]*b[i];
}

extern "C" void kernel_launch(void* const* d_in, const int* in_sizes, int n_in,
                              void* d_out, int out_size, void* d_ws, size_t ws_size,
                              hipStream_t stream) {
  (void)in_sizes; (void)n_in; (void)out_size; (void)ws_size;
  const float* x      = (const float*)d_in[0];
  const float* fc1_w  = (const float*)d_in[1];
  const float* fc1_b  = (const float*)d_in[2];
  const float* fc2_w  = (const float*)d_in[3];
  const float* fc2_b  = (const float*)d_in[4];
  const float* c1     = (const float*)d_in[5];
  const float* c2     = (const float*)d_in[6];
  const float* bn1_g  = (const float*)d_in[7];
  const float* bn1_b  = (const float*)d_in[8];
  const float* bn1_m  = (const float*)d_in[9];
  const float* bn1_v  = (const float*)d_in[10];
  const float* bn2_g  = (const float*)d_in[11];
  const float* bn2_b  = (const float*)d_in[12];
  const float* bn2_m  = (const float*)d_in[13];
  const float* bn2_v  = (const float*)d_in[14];
  const float* cgf_w  = (const float*)d_in[15];
  const float* cgf_b  = (const float*)d_in[16];
  const float* cgbn_g = (const float*)d_in[17];
  const float* cgbn_b = (const float*)d_in[18];
  const float* cgbn_m = (const float*)d_in[19];
  const float* cgbn_v = (const float*)d_in[20];
  const float* g1_w   = (const float*)d_in[21];
  const float* g1_b   = (const float*)d_in[22];
  const float* gbn_g  = (const float*)d_in[23];
  const float* gbn_b  = (const float*)d_in[24];
  const float* gbn_m  = (const float*)d_in[25];
  const float* gbn_v  = (const float*)d_in[26];
  const float* g2_w   = (const float*)d_in[27];
  const float* g2_b   = (const float*)d_in[28];
  const float* fc3_w  = (const float*)d_in[29];
  const float* fc3_b  = (const float*)d_in[30];

  char* w = (char*)d_ws;
  // region [0, 78643200): xn + w1b during phase 1; hbT after GEMM1
  u16*   xn    = (u16*)  (w + 0);                 // 39,321,600
  u16*   w1b   = (u16*)  (w + 39321600);          // 16,777,216
  u16*   hbT   = (u16*)  (w + 0);                 // 78,643,200 (after GEMM1)
  u16*   hb    = (u16*)  (w + 78643200);          // 78,643,200
  u16*   c1ext = (u16*)  (w + 157286400);         // 640*4096*2 = 5,242,880
  float* actx  = (float*)(w + 162529280);         // 9600*640*4 = 24,576,000
  u16*   actT  = (u16*)  (w + 187105280);         // 32*64*2400*2 = 9,830,400
  float* P2    = (float*)(w + 196935680);         // 5*32*512*64*4 = 20,971,520
  float* P     = (float*)(w + 196935680);         // skgemm partials reuse P2 region
  float* a_sum = (float*)(w + 217907200);         // 8,192
  float* vladn = (float*)(w + 217915392);         // 4,194,304
  float* y     = (float*)(w + 222109696);         // 262,144
  float* z     = (float*)(w + 222371840);         // 32,768
  float* gate  = (float*)(w + 222404608);         // 262,144
  float* yg    = (float*)(w + 222666752);         // 262,144
  // total ~222.9 MB

  k_l2norm<<<9600, 256, 0, stream>>>(x, xn);
  k_cvt<<<2048, 256, 0, stream>>>(fc1_w, w1b, (4096*2048)/4);
  k_transpose<<<dim3(128, 16), 256, 0, stream>>>(c1, c1ext);
  k_cvt<<<32, 256, 0, stream>>>(fc2_w, c1ext + (size_t)512*4096, (8*4096)/4);
  // GEMM1: h = xn @ fc1_w.T + fc1_b -> bf16 [9600][4096]; 256^2 pipelined kernel.
  // MT=38 (tail tile rows 9472..9727 read into w1b region - allocated, garbage
  // guarded at store), NT=16, grid 608, swz=2 (XCD supertile 19x4).
  k_gemm256<false, true><<<608, 512, 0, stream>>>(xn, w1b, fc1_b, nullptr, hb,
                                                  9600, 4096, 2048, 4096, 38, 16, 2);
  // hb -> hbT [32][512][2400] (overwrites xn/w1b)
  k_hbt<<<dim3(75, 8, 32), 256, 0, stream>>>(hb, hbT);
  // GEMM2+att: act_ext = h @ [c1 | fc2_w].T -> f32 [9600][640] (store cols < 520)
  k_gemm<true, false><<<375, 256, 0, stream>>>(hb, c1ext, nullptr, actx, nullptr, 640, 4096, 520, 75, 5, 0);
  // bn1 + softmax + att -> actT bf16 [32][64][2400]
  k_softmax<<<9600, 512, 0, stream>>>(actx, fc2_b, bn1_g, bn1_b, bn1_m, bn1_v, actT);
  k_asum<<<32, 256, 0, stream>>>(actT, a_sum);
  // vlad partials
  k_vlad<<<dim3(4, 32, 5), 256, 0, stream>>>(hbT, actT, P2);
  k_norm2<<<dim3(64, 32), 256, 0, stream>>>(P2, a_sum, c2, bn2_g, bn2_b, bn2_m, bn2_v, vladn);

  // cgf: y = BN(vladn @ cgf_w.T + cgf_b)   N=2048, K=32768, KSPLIT=64, KC=512
  k_skgemm<<<dim3(16, 64), 256, 0, stream>>>(vladn, cgf_w, P, 2048, 32768, 512, 2048);
  k_skred<1><<<256, 256, 0, stream>>>(P, 64, 2048, 2048, cgf_b, cgbn_g, cgbn_b, cgbn_m, cgbn_v, y);
  // g1: z = relu(BN(y @ g1_w.T + g1_b))    N=256, K=2048, KSPLIT=32, KC=64
  k_skgemm<<<dim3(2, 32), 256, 0, stream>>>(y, g1_w, P, 256, 2048, 64, 256);
  k_skred<2><<<32, 256, 0, stream>>>(P, 32, 256, 256, g1_b, gbn_g, gbn_b, gbn_m, gbn_v, z);
  // g2: gate = sigmoid(z @ g2_w.T + g2_b)  N=2048, K=256, KSPLIT=4, KC=64
  k_skgemm<<<dim3(16, 4), 256, 0, stream>>>(z, g2_w, P, 2048, 256, 64, 2048);
  k_skred<3><<<256, 256, 0, stream>>>(P, 4, 2048, 2048, g2_b, nullptr, nullptr, nullptr, nullptr, gate);
  k_mul<<<256, 256, 0, stream>>>(y, gate, yg, 65536);
  // fc3: out = yg @ fc3_w.T + fc3_b        N=3862 (pad 3968), K=2048, KSPLIT=16, KC=128
  k_skgemm<<<dim3(31, 16), 256, 0, stream>>>(yg, fc3_w, P, 3862, 2048, 128, 3968);
  k_skred<0><<<483, 256, 0, stream>>>(P, 16, 3862, 3968, fc3_b, nullptr, nullptr, nullptr, nullptr, (float*)d_out);
}

// Round 4
// 992.041 us; speedup vs baseline: 1.0290x; 1.0024x over previous
//
#include <hip/hip_runtime.h>

typedef unsigned short u16;
typedef unsigned int u32;
using f32x4 = __attribute__((ext_vector_type(4))) float;
using s16x8 = __attribute__((ext_vector_type(8))) short;
using u16x4 = __attribute__((ext_vector_type(4))) u16;

#define DEV __device__ __forceinline__

DEV float bf2f(u16 u) { union { u32 i; float f; } v; v.i = ((u32)u) << 16; return v.f; }
DEV u16 f2bf(float f) {
  union { float ff; u32 uu; } v; v.ff = f;
  u32 r = (v.uu + 0x7fffu + ((v.uu >> 16) & 1u)) >> 16;
  return (u16)r;
}

DEV void gl_lds16(const void* g, void* l) {
  __builtin_amdgcn_global_load_lds(
      (const __attribute__((address_space(1))) u32*)g,
      (__attribute__((address_space(3))) u32*)l, 16, 0, 0);
}

DEV void BAR() { __builtin_amdgcn_s_barrier(); __builtin_amdgcn_sched_barrier(0); }
DEV void VM6() { asm volatile("s_waitcnt vmcnt(6)" ::: "memory"); }
DEV void VM0() { asm volatile("s_waitcnt vmcnt(0)" ::: "memory"); }
DEV void PRIO1() { __builtin_amdgcn_s_setprio(1); }
DEV void PRIO0() { __builtin_amdgcn_s_setprio(0); }
#define SBAR0() __builtin_amdgcn_sched_barrier(0)
// counted lgkm wait + scheduling fence (rule #18)
#define LGKM(N_) do { asm volatile("s_waitcnt lgkmcnt(" #N_ ")" ::: "memory"); SBAR0(); } while (0)

// inline-asm ds_read_b128: invisible to the compiler's LDS<->global_load_lds
// aliasing model, so no conservative vmem drains get inserted before it.
#define DSR(d, a, OFF) asm volatile("ds_read_b128 %0, %1 offset:" #OFF \
                                    : "=&v"(d) : "v"(a))
#define DSR4(D_, a_) do { unsigned aa_ = (a_);                                 \
  DSR(D_[0], aa_, 0);    DSR(D_[1], aa_, 2048);                                \
  DSR(D_[2], aa_, 4096); DSR(D_[3], aa_, 6144); } while (0)

// 16 MFMA: 4 A-frags x 4 B-frags into acc rows R_..R_+3 (R_ literal)
#define MF16(FA_, FB_, R_) do { PRIO1();                                       \
  _Pragma("unroll")                                                            \
  for (int i_ = 0; i_ < 4; i_++) {                                             \
    acc[(R_)+i_][0] = __builtin_amdgcn_mfma_f32_16x16x32_bf16(FA_[i_], FB_[0], acc[(R_)+i_][0], 0, 0, 0); \
    acc[(R_)+i_][1] = __builtin_amdgcn_mfma_f32_16x16x32_bf16(FA_[i_], FB_[1], acc[(R_)+i_][1], 0, 0, 0); \
    acc[(R_)+i_][2] = __builtin_amdgcn_mfma_f32_16x16x32_bf16(FA_[i_], FB_[2], acc[(R_)+i_][2], 0, 0, 0); \
    acc[(R_)+i_][3] = __builtin_amdgcn_mfma_f32_16x16x32_bf16(FA_[i_], FB_[3], acc[(R_)+i_][3], 0, 0, 0); \
  }                                                                            \
  PRIO0(); } while (0)

// ---------------- L2 normalize per frame, emit bf16 ----------------
__global__ __launch_bounds__(256) void k_l2norm(const float* __restrict__ x, u16* __restrict__ xn) {
  int r = blockIdx.x, t = threadIdx.x;
  const float* xr = x + (size_t)r * 2048;
  float v[8], s = 0.f;
#pragma unroll
  for (int i = 0; i < 8; i++) { v[i] = xr[t + i*256]; s += v[i]*v[i]; }
#pragma unroll
  for (int off = 32; off > 0; off >>= 1) s += __shfl_xor(s, off, 64);
  __shared__ float red[4];
  if ((t & 63) == 0) red[t >> 6] = s;
  __syncthreads();
  float inv = 1.f / fmaxf(sqrtf(red[0]+red[1]+red[2]+red[3]), 1e-12f);
  u16* xo = xn + (size_t)r * 2048;
#pragma unroll
  for (int i = 0; i < 8; i++) xo[t + i*256] = f2bf(v[i]*inv);
}

// ---------------- f32 -> bf16 ----------------
__global__ void k_cvt(const float* __restrict__ in, u16* __restrict__ out, int n4) {
  int i = blockIdx.x*256 + threadIdx.x, st = gridDim.x*256;
  for (; i < n4; i += st) {
    f32x4 v = ((const f32x4*)in)[i];
    u16x4 o;
    o[0] = f2bf(v[0]); o[1] = f2bf(v[1]); o[2] = f2bf(v[2]); o[3] = f2bf(v[3]);
    ((u16x4*)out)[i] = o;
  }
}

// ---------------- c1 [4096][512] -> c1ext bf16 rows 0..511 [640][4096] ----------------
__global__ __launch_bounds__(256) void k_transpose(const float* __restrict__ c1, u16* __restrict__ c1t) {
  __shared__ float tile[32][33];
  int k0 = blockIdx.x*32, n0 = blockIdx.y*32;
  int tx = threadIdx.x & 31, ty = threadIdx.x >> 5;
  for (int i = ty; i < 32; i += 8) tile[i][tx] = c1[(size_t)(k0+i)*512 + n0 + tx];
  __syncthreads();
  for (int i = ty; i < 32; i += 8) c1t[(size_t)(n0+i)*4096 + k0 + tx] = f2bf(tile[tx][i]);
}

// ---------------- bf16 MFMA NT GEMM, 128x128 tile (kept for GEMM2) ----------------
template<bool WF32, bool WBF16>
__global__ __launch_bounds__(256) void k_gemm(
    const u16* __restrict__ A, const u16* __restrict__ Bt, const float* __restrict__ bias,
    float* __restrict__ Cf, u16* __restrict__ Cb, int N, int K, int Nlim,
    int MT, int NT, int swz) {
  __shared__ u16 As[128*32];
  __shared__ u16 Bs[128*32];
  int bid = blockIdx.x, mt, nt;
  if (swz) {
    int mg = (MT + 7) >> 3;
    int gid = bid >> 5, gl = bid & 31;
    mt = (gid % mg)*8 + (gl & 7);
    nt = (gid / mg)*4 + (gl >> 3);
    if (mt >= MT) return;
  } else { mt = bid % MT; nt = bid / MT; }
  int t = threadIdx.x, wv = t >> 6;
  int quad = (t & 63) >> 4, lr = t & 15;
  size_t m0 = (size_t)mt * 128, n0 = (size_t)nt * 128;
  int wm = wv & 1, wn = wv >> 1;
  int srow = t >> 2;
  int scol = (((t & 3) ^ ((t >> 3) & 3)) * 8);   // XOR-swizzled k-chunk
  const u16* gA = A + (m0 + srow)*(size_t)K + scol;
  const u16* gB = Bt + (n0 + srow)*(size_t)K + scol;
  u16* lA = &As[wv*512];
  u16* lB = &Bs[wv*512];
  int xq = (quad ^ ((lr >> 1) & 3)) * 8;          // matching frag-read chunk
  f32x4 acc[4][4];
#pragma unroll
  for (int i = 0; i < 4; i++)
#pragma unroll
    for (int j = 0; j < 4; j++) acc[i][j] = (f32x4){0.f,0.f,0.f,0.f};
  for (int k0 = 0; k0 < K; k0 += 32) {
    gl_lds16(gA + k0, lA);
    gl_lds16(gA + (size_t)64*K + k0, lA + 2048);
    gl_lds16(gB + k0, lB);
    gl_lds16(gB + (size_t)64*K + k0, lB + 2048);
    __syncthreads();
    s16x8 af[4], bfr[4];
#pragma unroll
    for (int i = 0; i < 4; i++) {
      af[i]  = *(const s16x8*)&As[(wm*64 + i*16 + lr)*32 + xq];
      bfr[i] = *(const s16x8*)&Bs[(wn*64 + i*16 + lr)*32 + xq];
    }
#pragma unroll
    for (int i = 0; i < 4; i++)
#pragma unroll
      for (int j = 0; j < 4; j++)
        acc[i][j] = __builtin_amdgcn_mfma_f32_16x16x32_bf16(af[i], bfr[j], acc[i][j], 0, 0, 0);
    __syncthreads();
  }
#pragma unroll
  for (int j = 0; j < 4; j++) {
    size_t nn = n0 + wn*64 + j*16 + lr;
    if ((int)nn >= Nlim) continue;
    float bj = bias ? bias[nn] : 0.f;
#pragma unroll
    for (int i = 0; i < 4; i++) {
      size_t mr = m0 + wm*64 + i*16 + quad*4;
#pragma unroll
      for (int r = 0; r < 4; r++) {
        float v = acc[i][j][r] + bj;
        if (WF32)  Cf[(mr + r)*N + nn] = v;
        if (WBF16) Cb[(mr + r)*N + nn] = f2bf(v);
      }
    }
  }
}

// ---------------- 256x256 bf16 MFMA GEMM, fragment-pipelined (phase-ahead reads) ----------------
// C[m,n] = sum_k A[m,k]*Bt[n,k] (+bias). 512 threads = 8 waves (2M x 4N),
// double-buffered 128 KiB LDS, counted vmcnt(6) keeps staging in flight.
// Each K-tile = 4 phases of 16 MFMA (A-half x k-slice). Phase p ISSUES the
// ds_reads for phase p+1 first, waits lgkmcnt(#just-issued) for phase p's
// operands (in-order DS completion), then MFMAs -- operands are always one
// phase (~600 cyc) in flight ahead, so LDS pipe and matrix pipe overlap.
// The buffer-swap window (BAR; stage trio; VM6; BAR) sits after P2 so P3 can
// prefetch the NEXT tile's P0 operands across it.
// Fragment banks: FAA/FAB, FBA/FBB ping-pong (static names, rule #20).
// LDS chunk swizzle (both sides): logical 16B chunk c of row r at phys c^(r&7).
// swz==2: bijective XCD supertile map (19mt x 4nt per XCD; MT=38,NT=16).
template<bool WF32, bool WBF16>
__global__ __launch_bounds__(512, 2) void k_gemm256(
    const u16* __restrict__ A, const u16* __restrict__ Bt, const float* __restrict__ bias,
    float* __restrict__ Cf, u16* __restrict__ Cb,
    int M, int N, int K, int Nlim, int MT, int NT, int swz) {
  constexpr int TILE = 256*64;                 // u16 elems per matrix per buffer
  __shared__ u16 lds[4*TILE];                  // A0|B0|A1|B1, 32 KiB each
  int bid = blockIdx.x, mt, nt;
  if (swz == 2) {
    int x = bid & 7, w2 = bid >> 3;
    mt = (x & 1)*19 + w2 % 19;
    nt = (x >> 1)*4 + w2 / 19;
  } else if (swz == 1) {
    int c = (MT*NT) >> 3; int b2 = (bid & 7)*c + (bid >> 3);
    mt = b2 % MT; nt = b2 / MT;
  } else { mt = bid % MT; nt = bid / MT; }
  int t = threadIdx.x, wv = t >> 6, lane = t & 63;
  int quad = lane >> 4, lr = lane & 15;
  int wm = wv >> 2, wn = wv & 3;               // 2M x 4N waves
  size_t m0 = (size_t)mt * 256, n0 = (size_t)nt * 256;
  // staging: lane l covers (row 8*wv + (l>>3), phys chunk l&7); source pre-swizzled
  int srow = wv*8 + (lane >> 3);
  int schunk = ((lane & 7) ^ (lane >> 3)) * 8;
  const u16* gA = A  + (size_t)(m0 + srow)*K + schunk;
  const u16* gB = Bt + (size_t)(n0 + srow)*K + schunk;
  size_t row64 = (size_t)64 * K;
  int lofs = wv*512;                           // wave's 1KiB slot per 64-row group
  // fragment read addresses (bytes); A-half1 = +8192, k-slice1 = ^64, buffer flip = ^0x10000
  unsigned ldsB = (unsigned)(size_t)lds;
  unsigned pc = (unsigned)((quad ^ (lr & 7)) << 4);
  unsigned aCur = ldsB + (unsigned)((wm*128 + lr)*128) + pc;
  unsigned bCur = ldsB + 32768u + (unsigned)((wn*64 + lr)*128) + pc;
  f32x4 acc[8][4];
#pragma unroll
  for (int i = 0; i < 8; i++)
#pragma unroll
    for (int j = 0; j < 4; j++) acc[i][j] = (f32x4){0.f,0.f,0.f,0.f};

  int T = K >> 6;
  u16* A0 = lds;            u16* B0 = lds + TILE;
  u16* A1 = lds + 2*TILE;   u16* B1 = lds + 3*TILE;
  // ---- prologue staging: tile0 full (8) + tile1 trio (6) ----
#pragma unroll
  for (int q = 0; q < 4; q++) gl_lds16(gA + q*row64, A0 + q*4096 + lofs);
#pragma unroll
  for (int q = 0; q < 4; q++) gl_lds16(gB + q*row64, B0 + q*4096 + lofs);
#pragma unroll
  for (int q = 0; q < 4; q++) gl_lds16(gA + 64 + q*row64, A1 + q*4096 + lofs);
  gl_lds16(gB + 64,          B1 + lofs);
  gl_lds16(gB + 64 + row64,  B1 + 4096 + lofs);
  VM6();          // tile0 resident; tile1 trio stays in flight
  BAR();

  // ---- prologue fragment reads: P0 operands of tile0 ----
  s16x8 FAA[4], FAB[4], FBA[4], FBB[4];
  DSR4(FBA, bCur);
  DSR4(FAA, aCur);
  SBAR0();

  for (int tt = 0; tt < T; ++tt) {
    // ---- P0: read fa1(s0); MFMA fa0(s0) x fb(s0) -> acc[0..3] ----
    DSR4(FAB, aCur + 8192u);
    SBAR0();
    LGKM(4);
    MF16(FAA, FBA, 0);
    // ---- P1: read fb(s1), fa0(s1); issue Bh1(tt+1); MFMA fa1(s0) x fb(s0) -> acc[4..7] ----
    DSR4(FBB, bCur ^ 64u);
    DSR4(FAA, aCur ^ 64u);
    if (tt + 1 < T) {
      const u16* gB1 = gB + (size_t)(tt + 1)*64;
      u16* Bq = lds + (((tt + 1) & 1)*2 + 1)*TILE;
      gl_lds16(gB1 + 2*row64, Bq + 2*4096 + lofs);
      gl_lds16(gB1 + 3*row64, Bq + 3*4096 + lofs);
    }
    SBAR0();
    LGKM(8);
    MF16(FAB, FBA, 4);
    // ---- P2: read fa1(s1); MFMA fa0(s1) x fb(s1) -> acc[0..3] ----
    DSR4(FAB, (aCur + 8192u) ^ 64u);
    SBAR0();
    LGKM(4);
    MF16(FAA, FBB, 0);
    // ---- buffer-swap window: all reads of cur buffer issued -> stageable ----
    BAR();
    if (tt + 2 < T) {
      const u16* gA2 = gA + (size_t)(tt + 2)*64;
      const u16* gB2 = gB + (size_t)(tt + 2)*64;
      u16* Ap = lds + ((tt & 1)*2)*TILE;
      u16* Bp = Ap + TILE;
#pragma unroll
      for (int q = 0; q < 4; q++) gl_lds16(gA2 + q*row64, Ap + q*4096 + lofs);
      gl_lds16(gB2,         Bp + lofs);
      gl_lds16(gB2 + row64, Bp + 4096 + lofs);
      VM6();                   // tile tt+1 fully landed; trio(tt+2) in flight
    } else if (tt + 1 < T) {
      VM0();                   // tail: drain for final tile
    }
    if (tt + 1 < T) BAR();     // next buffer resident chip-wide
    // ---- P3: read NEXT tile's P0 operands; MFMA fa1(s1) x fb(s1) -> acc[4..7] ----
    if (tt + 1 < T) {
      DSR4(FBA, bCur ^ 0x10000u);
      DSR4(FAA, aCur ^ 0x10000u);
      SBAR0();
      LGKM(8);
    } else {
      LGKM(0);
    }
    MF16(FAB, FBB, 4);
    aCur ^= 0x10000u; bCur ^= 0x10000u;
  }

  // ---- epilogue (row-contiguous store order: i,r outer, j inner) ----
  float bj[4];
#pragma unroll
  for (int j = 0; j < 4; j++) {
    int nn = (int)n0 + wn*64 + j*16 + lr;
    bj[j] = (bias && nn < Nlim) ? bias[nn] : 0.f;
  }
#pragma unroll
  for (int i = 0; i < 8; i++) {
    int mrb = (int)m0 + wm*128 + i*16 + quad*4;
#pragma unroll
    for (int r = 0; r < 4; r++) {
      int mr = mrb + r;
      if (mr >= M) continue;
#pragma unroll
      for (int j = 0; j < 4; j++) {
        int nn = (int)n0 + wn*64 + j*16 + lr;
        if (nn >= Nlim) continue;
        float v = acc[i][j][r] + bj[j];
        if (WF32)  Cf[(size_t)mr*N + nn] = v;
        if (WBF16) Cb[(size_t)mr*N + nn] = f2bf(v);
      }
    }
  }
}

// ---------------- hb [9600][4096] -> hbT [32][512][2400] (bf16) ----------------
__global__ __launch_bounds__(256) void k_hbt(const u16* __restrict__ hb, u16* __restrict__ hbT) {
  __shared__ u16 tile[64*33];
  int nt = blockIdx.x, ft = blockIdx.y, b = blockIdx.z, t = threadIdx.x;
  int n0 = nt*32, f0 = ft*64;
  int rrel = t >> 6, g = (t >> 3) & 7, fi = (t & 7)*8;
  const u16* src = hb + ((size_t)(b*300 + (n0 >> 3) + rrel))*4096 + g*512 + f0 + fi;
  u16 v[8];
  *(u16x4*)v = *(const u16x4*)src;
  *(u16x4*)(v+4) = *(const u16x4*)(src+4);
  int nl = rrel*8 + g;
#pragma unroll
  for (int e = 0; e < 8; e++) tile[(fi+e)*33 + nl] = v[e];
  __syncthreads();
  int f = t >> 2, nc = (t & 3)*8;
  u16 o[8];
#pragma unroll
  for (int e = 0; e < 8; e++) o[e] = tile[f*33 + nc + e];
  u16* dst = hbT + ((size_t)b*512 + f0 + f)*2400 + n0 + nc;
  *(u16x4*)dst = *(u16x4*)o;
  *(u16x4*)(dst+4) = *(u16x4*)(o+4);
}

// ---------------- bn1 + softmax(K=64) + att(from ext cols) -> actT bf16 [32][64][2400] ----------------
__global__ __launch_bounds__(512) void k_softmax(const float* __restrict__ act_ext,
    const float* __restrict__ fc2_b,
    const float* __restrict__ g, const float* __restrict__ b,
    const float* __restrict__ mu, const float* __restrict__ var, u16* __restrict__ actT) {
  int m = blockIdx.x, t = threadIdx.x;
  int bb = m / 300, fr = m - bb*300;
  int gi = t >> 6, k = t & 63, c = t;
  float v = act_ext[(size_t)m*640 + c];
  v = (v - mu[c]) * rsqrtf(var[c] + 1e-5f) * g[c] + b[c];
  float mx = v;
#pragma unroll
  for (int off = 32; off > 0; off >>= 1) mx = fmaxf(mx, __shfl_xor(mx, off, 64));
  float e = __expf(v - mx);
  float s = e;
#pragma unroll
  for (int off = 32; off > 0; off >>= 1) s += __shfl_xor(s, off, 64);
  float attl = act_ext[(size_t)m*640 + 512 + gi] + fc2_b[gi];
  float attv = 1.f / (1.f + __expf(-attl));
  float r = (e / s) * attv;
  __shared__ u16 st[64*9];
  st[k*9 + gi] = f2bf(r);
  __syncthreads();
  if (t < 64) {
    u16 o[8];
#pragma unroll
    for (int e2 = 0; e2 < 8; e2++) o[e2] = st[t*9 + e2];
    u16* dst = actT + ((size_t)bb*64 + t)*2400 + fr*8;
    *(u16x4*)dst = *(u16x4*)o;
    *(u16x4*)(dst+4) = *(u16x4*)(o+4);
  }
}

// ---------------- a_sum[b,k] = sum_n actT[b,k,n] ----------------
__global__ __launch_bounds__(256) void k_asum(const u16* __restrict__ actT, float* __restrict__ a_sum) {
  int b = blockIdx.x, t = threadIdx.x;
  int k = t >> 2, q = t & 3;
  const u16* p = actT + ((size_t)b*64 + k)*2400 + q*600;
  float acc = 0.f;
  for (int j = 0; j < 600; j += 8) {
    u16x4 a0 = *(const u16x4*)(p + j);
    u16x4 a1 = *(const u16x4*)(p + j + 4);
    acc += bf2f(a0[0])+bf2f(a0[1])+bf2f(a0[2])+bf2f(a0[3])
         + bf2f(a1[0])+bf2f(a1[1])+bf2f(a1[2])+bf2f(a1[3]);
  }
  __shared__ float red[256];
  red[t] = acc;
  __syncthreads();
  if (t < 64) a_sum[b*64 + t] = red[t*4] + red[t*4+1] + red[t*4+2] + red[t*4+3];
}

// ---------------- vlad MFMA: P2[ns][b][f][k] = sum_{n in chunk} hbT[b][f][n]*actT[b][k][n] ----------------
__global__ __launch_bounds__(256) void k_vlad(const u16* __restrict__ hbT, const u16* __restrict__ actT,
                                              float* __restrict__ P2) {
  __shared__ u16 As[128*32];
  __shared__ u16 Bs[64*32];
  int t = threadIdx.x, wv = t >> 6;
  int quad = (t & 63) >> 4, lr = t & 15;
  int ft = blockIdx.x, b = blockIdx.y, ns = blockIdx.z;
  int wm = wv & 1, wn = wv >> 1;
  int srow = t >> 2;
  int scol = (((t & 3) ^ ((t >> 3) & 3)) * 8);
  int xq = (quad ^ ((lr >> 1) & 3)) * 8;
  const u16* gA = hbT + ((size_t)b*512 + ft*128 + srow)*2400 + ns*480 + scol;
  const u16* gB = actT + ((size_t)b*64 + srow)*2400 + ns*480 + scol;
  u16* lA = &As[wv*512];
  u16* lB = &Bs[wv*512];
  f32x4 acc[4][2];
#pragma unroll
  for (int i = 0; i < 4; i++)
#pragma unroll
    for (int j = 0; j < 2; j++) acc[i][j] = (f32x4){0.f,0.f,0.f,0.f};
  for (int k0 = 0; k0 < 480; k0 += 32) {
    gl_lds16(gA + k0, lA);
    gl_lds16(gA + (size_t)64*2400 + k0, lA + 2048);
    gl_lds16(gB + k0, lB);
    __syncthreads();
    s16x8 af[4], bfr[2];
#pragma unroll
    for (int i = 0; i < 4; i++)
      af[i] = *(const s16x8*)&As[(wm*64 + i*16 + lr)*32 + xq];
#pragma unroll
    for (int j = 0; j < 2; j++)
      bfr[j] = *(const s16x8*)&Bs[(wn*32 + j*16 + lr)*32 + xq];
#pragma unroll
    for (int i = 0; i < 4; i++)
#pragma unroll
      for (int j = 0; j < 2; j++)
        acc[i][j] = __builtin_amdgcn_mfma_f32_16x16x32_bf16(af[i], bfr[j], acc[i][j], 0, 0, 0);
    __syncthreads();
  }
  size_t base = ((size_t)ns*32 + b)*512*64;
#pragma unroll
  for (int j = 0; j < 2; j++) {
    int kc = wn*32 + j*16 + lr;
#pragma unroll
    for (int i = 0; i < 4; i++) {
      int f = ft*128 + wm*64 + i*16 + quad*4;
#pragma unroll
      for (int r = 0; r < 4; r++)
        P2[base + (size_t)(f + r)*64 + kc] = acc[i][j][r];
    }
  }
}

// ---------------- sum partials, subtract a, intra-norm over f, bn2 -> vladn [32][32768] ----------------
__global__ __launch_bounds__(256) void k_norm2(const float* __restrict__ P2, const float* __restrict__ a_sum,
    const float* __restrict__ c2, const float* __restrict__ g, const float* __restrict__ b,
    const float* __restrict__ mu, const float* __restrict__ var, float* __restrict__ out) {
  int k = blockIdx.x, bb = blockIdx.y, t = threadIdx.x;
  float as = a_sum[bb*64 + k];
  int f0 = t, f1 = t + 256;
  const size_t PS = (size_t)32*512*64;
  size_t base = (size_t)bb*512*64;
  float x0 = 0.f, x1 = 0.f;
#pragma unroll
  for (int ns = 0; ns < 5; ns++) {
    x0 += P2[ns*PS + base + (size_t)f0*64 + k];
    x1 += P2[ns*PS + base + (size_t)f1*64 + k];
  }
  x0 -= as * c2[f0*64 + k];
  x1 -= as * c2[f1*64 + k];
  float s = x0*x0 + x1*x1;
#pragma unroll
  for (int off = 32; off > 0; off >>= 1) s += __shfl_xor(s, off, 64);
  __shared__ float red[4];
  if ((t & 63) == 0) red[t >> 6] = s;
  __syncthreads();
  float inv = 1.f / fmaxf(sqrtf(red[0]+red[1]+red[2]+red[3]), 1e-12f);
  int c0 = f0*64 + k, c1 = f1*64 + k;
  out[(size_t)bb*32768 + c0] = (x0*inv - mu[c0]) * rsqrtf(var[c0]+1e-5f) * g[c0] + b[c0];
  out[(size_t)bb*32768 + c1] = (x1*inv - mu[c1]) * rsqrtf(var[c1]+1e-5f) * g[c1] + b[c1];
}

// ---------------- split-K small-M MFMA GEMM ----------------
__global__ __launch_bounds__(256) void k_skgemm(
    const float* __restrict__ A, const float* __restrict__ W,
    float* __restrict__ P, int N, int K, int KC, int Npad) {
  constexpr int LDB = 72;
  __shared__ u16 Bs[128*LDB];
  __shared__ u16 As[32*LDB];
  int t = threadIdx.x;
  int wv = t >> 6, quad = (t & 63) >> 4, lr = t & 15;
  int n0 = blockIdx.x * 128;
  size_t kc0 = (size_t)blockIdx.y * KC;
  f32x4 acc[2][2];
#pragma unroll
  for (int i = 0; i < 2; i++)
#pragma unroll
    for (int j = 0; j < 2; j++) acc[i][j] = (f32x4){0.f,0.f,0.f,0.f};
  int wl[8]; size_t wg[8];
#pragma unroll
  for (int i = 0; i < 8; i++) {
    int slot = i*256 + t;
    int r = slot >> 4, q = slot & 15;
    int row = n0 + r; if (row >= N) row = N - 1;
    wl[i] = r*LDB + q*4;
    wg[i] = (size_t)row*K + kc0 + q*4;
  }
  int al[2]; size_t ag[2];
#pragma unroll
  for (int i = 0; i < 2; i++) {
    int slot = i*256 + t;
    int r = slot >> 4, q = slot & 15;
    al[i] = r*LDB + q*4;
    ag[i] = (size_t)r*K + kc0 + q*4;
  }
  int nst = KC >> 6;
  f32x4 wv4[8], av4[2];
#pragma unroll
  for (int i = 0; i < 8; i++) wv4[i] = *(const f32x4*)(W + wg[i]);
#pragma unroll
  for (int i = 0; i < 2; i++) av4[i] = *(const f32x4*)(A + ag[i]);
  for (int s = 0; s < nst; s++) {
    if (s) __syncthreads();
#pragma unroll
    for (int i = 0; i < 8; i++) {
      u16x4 o;
      o[0] = f2bf(wv4[i][0]); o[1] = f2bf(wv4[i][1]);
      o[2] = f2bf(wv4[i][2]); o[3] = f2bf(wv4[i][3]);
      *(u16x4*)&Bs[wl[i]] = o;
    }
#pragma unroll
    for (int i = 0; i < 2; i++) {
      u16x4 o;
      o[0] = f2bf(av4[i][0]); o[1] = f2bf(av4[i][1]);
      o[2] = f2bf(av4[i][2]); o[3] = f2bf(av4[i][3]);
      *(u16x4*)&As[al[i]] = o;
    }
    __syncthreads();
    if (s + 1 < nst) {
      int off = (s + 1) * 64;
#pragma unroll
      for (int i = 0; i < 8; i++) wv4[i] = *(const f32x4*)(W + wg[i] + off);
#pragma unroll
      for (int i = 0; i < 2; i++) av4[i] = *(const f32x4*)(A + ag[i] + off);
    }
#pragma unroll
    for (int ks = 0; ks < 2; ks++) {
      s16x8 af[2];
#pragma unroll
      for (int i = 0; i < 2; i++)
        af[i] = *(const s16x8*)&As[(i*16 + lr)*LDB + ks*32 + quad*8];
#pragma unroll
      for (int j = 0; j < 2; j++) {
        s16x8 bf = *(const s16x8*)&Bs[(wv*32 + j*16 + lr)*LDB + ks*32 + quad*8];
#pragma unroll
        for (int i = 0; i < 2; i++)
          acc[i][j] = __builtin_amdgcn_mfma_f32_16x16x32_bf16(af[i], bf, acc[i][j], 0, 0, 0);
      }
    }
  }
#pragma unroll
  for (int i = 0; i < 2; i++)
#pragma unroll
    for (int j = 0; j < 2; j++) {
      int n = n0 + wv*32 + j*16 + lr;
#pragma unroll
      for (int r = 0; r < 4; r++) {
        int m = i*16 + quad*4 + r;
        P[((size_t)blockIdx.y*32 + m)*Npad + n] = acc[i][j][r];
      }
    }
}

// ---------------- split-K reduce + epilogue ----------------
template<int EPI>
__global__ __launch_bounds__(256) void k_skred(const float* __restrict__ P, int KSPLIT, int N, int Npad,
    const float* __restrict__ bias, const float* __restrict__ bg, const float* __restrict__ bb,
    const float* __restrict__ bm, const float* __restrict__ bv, float* __restrict__ C) {
  int idx = blockIdx.x*256 + threadIdx.x;
  if (idx >= 32*N) return;
  int m = idx / N, n = idx - m*N;
  float s = 0.f;
  for (int k = 0; k < KSPLIT; k++) s += P[((size_t)k*32 + m)*Npad + n];
  float v = s + (bias ? bias[n] : 0.f);
  if (EPI == 1 || EPI == 2) {
    v = (v - bm[n]) * rsqrtf(bv[n] + 1e-5f) * bg[n] + bb[n];
    if (EPI == 2) v = fmaxf(v, 0.f);
  } else if (EPI == 3) {
    v = 1.f / (1.f + __expf(-v));
  }
  C[idx] = v;
}

// ---------------- elementwise multiply ----------------
__global__ void k_mul(const float* __restrict__ a, const float* __restrict__ b, float* __restrict__ o, int n) {
  int i = blockIdx.x*256 + threadIdx.x;
  if (i < n) o[i] = a[i]*b[i];
}

extern "C" void kernel_launch(void* const* d_in, const int* in_sizes, int n_in,
                              void* d_out, int out_size, void* d_ws, size_t ws_size,
                              hipStream_t stream) {
  (void)in_sizes; (void)n_in; (void)out_size; (void)ws_size;
  const float* x      = (const float*)d_in[0];
  const float* fc1_w  = (const float*)d_in[1];
  const float* fc1_b  = (const float*)d_in[2];
  const float* fc2_w  = (const float*)d_in[3];
  const float* fc2_b  = (const float*)d_in[4];
  const float* c1     = (const float*)d_in[5];
  const float* c2     = (const float*)d_in[6];
  const float* bn1_g  = (const float*)d_in[7];
  const float* bn1_b  = (const float*)d_in[8];
  const float* bn1_m  = (const float*)d_in[9];
  const float* bn1_v  = (const float*)d_in[10];
  const float* bn2_g  = (const float*)d_in[11];
  const float* bn2_b  = (const float*)d_in[12];
  const float* bn2_m  = (const float*)d_in[13];
  const float* bn2_v  = (const float*)d_in[14];
  const float* cgf_w  = (const float*)d_in[15];
  const float* cgf_b  = (const float*)d_in[16];
  const float* cgbn_g = (const float*)d_in[17];
  const float* cgbn_b = (const float*)d_in[18];
  const float* cgbn_m = (const float*)d_in[19];
  const float* cgbn_v = (const float*)d_in[20];
  const float* g1_w   = (const float*)d_in[21];
  const float* g1_b   = (const float*)d_in[22];
  const float* gbn_g  = (const float*)d_in[23];
  const float* gbn_b  = (const float*)d_in[24];
  const float* gbn_m  = (const float*)d_in[25];
  const float* gbn_v  = (const float*)d_in[26];
  const float* g2_w   = (const float*)d_in[27];
  const float* g2_b   = (const float*)d_in[28];
  const float* fc3_w  = (const float*)d_in[29];
  const float* fc3_b  = (const float*)d_in[30];

  char* w = (char*)d_ws;
  // region [0, 78643200): xn + w1b during phase 1; hbT after GEMM1
  u16*   xn    = (u16*)  (w + 0);                 // 39,321,600
  u16*   w1b   = (u16*)  (w + 39321600);          // 16,777,216
  u16*   hbT   = (u16*)  (w + 0);                 // 78,643,200 (after GEMM1)
  u16*   hb    = (u16*)  (w + 78643200);          // 78,643,200
  u16*   c1ext = (u16*)  (w + 157286400);         // 640*4096*2 = 5,242,880
  float* actx  = (float*)(w + 162529280);         // 9600*640*4 = 24,576,000
  u16*   actT  = (u16*)  (w + 187105280);         // 32*64*2400*2 = 9,830,400
  float* P2    = (float*)(w + 196935680);         // 5*32*512*64*4 = 20,971,520
  float* P     = (float*)(w + 196935680);         // skgemm partials reuse P2 region
  float* a_sum = (float*)(w + 217907200);         // 8,192
  float* vladn = (float*)(w + 217915392);         // 4,194,304
  float* y     = (float*)(w + 222109696);         // 262,144
  float* z     = (float*)(w + 222371840);         // 32,768
  float* gate  = (float*)(w + 222404608);         // 262,144
  float* yg    = (float*)(w + 222666752);         // 262,144
  // total ~222.9 MB

  k_l2norm<<<9600, 256, 0, stream>>>(x, xn);
  k_cvt<<<2048, 256, 0, stream>>>(fc1_w, w1b, (4096*2048)/4);
  k_transpose<<<dim3(128, 16), 256, 0, stream>>>(c1, c1ext);
  k_cvt<<<32, 256, 0, stream>>>(fc2_w, c1ext + (size_t)512*4096, (8*4096)/4);
  // GEMM1: h = xn @ fc1_w.T + fc1_b -> bf16 [9600][4096]; 256^2 fragment-pipelined.
  // MT=38 (tail tile rows 9472..9727 read into w1b region - allocated, garbage
  // guarded at store), NT=16, grid 608, swz=2 (XCD supertile 19x4).
  k_gemm256<false, true><<<608, 512, 0, stream>>>(xn, w1b, fc1_b, nullptr, hb,
                                                  9600, 4096, 2048, 4096, 38, 16, 2);
  // hb -> hbT [32][512][2400] (overwrites xn/w1b)
  k_hbt<<<dim3(75, 8, 32), 256, 0, stream>>>(hb, hbT);
  // GEMM2+att: act_ext = h @ [c1 | fc2_w].T -> f32 [9600][640] (store cols < 520)
  k_gemm<true, false><<<375, 256, 0, stream>>>(hb, c1ext, nullptr, actx, nullptr, 640, 4096, 520, 75, 5, 0);
  // bn1 + softmax + att -> actT bf16 [32][64][2400]
  k_softmax<<<9600, 512, 0, stream>>>(actx, fc2_b, bn1_g, bn1_b, bn1_m, bn1_v, actT);
  k_asum<<<32, 256, 0, stream>>>(actT, a_sum);
  // vlad partials
  k_vlad<<<dim3(4, 32, 5), 256, 0, stream>>>(hbT, actT, P2);
  k_norm2<<<dim3(64, 32), 256, 0, stream>>>(P2, a_sum, c2, bn2_g, bn2_b, bn2_m, bn2_v, vladn);

  // cgf: y = BN(vladn @ cgf_w.T + cgf_b)   N=2048, K=32768, KSPLIT=64, KC=512
  k_skgemm<<<dim3(16, 64), 256, 0, stream>>>(vladn, cgf_w, P, 2048, 32768, 512, 2048);
  k_skred<1><<<256, 256, 0, stream>>>(P, 64, 2048, 2048, cgf_b, cgbn_g, cgbn_b, cgbn_m, cgbn_v, y);
  // g1: z = relu(BN(y @ g1_w.T + g1_b))    N=256, K=2048, KSPLIT=32, KC=64
  k_skgemm<<<dim3(2, 32), 256, 0, stream>>>(y, g1_w, P, 256, 2048, 64, 256);
  k_skred<2><<<32, 256, 0, stream>>>(P, 32, 256, 256, g1_b, gbn_g, gbn_b, gbn_m, gbn_v, z);
  // g2: gate = sigmoid(z @ g2_w.T + g2_b)  N=2048, K=256, KSPLIT=4, KC=64
  k_skgemm<<<dim3(16, 4), 256, 0, stream>>>(z, g2_w, P, 2048, 256, 64, 2048);
  k_skred<3><<<256, 256, 0, stream>>>(P, 4, 2048, 2048, g2_b, nullptr, nullptr, nullptr, nullptr, gate);
  k_mul<<<256, 256, 0, stream>>>(y, gate, yg, 65536);
  // fc3: out = yg @ fc3_w.T + fc3_b        N=3862 (pad 3968), K=2048, KSPLIT=16, KC=128
  k_skgemm<<<dim3(31, 16), 256, 0, stream>>>(yg, fc3_w, P, 3862, 2048, 128, 3968);
  k_skred<0><<<483, 256, 0, stream>>>(P, 16, 3862, 3968, fc3_b, nullptr, nullptr, nullptr, nullptr, (float*)d_out);
}